// Round 6
// baseline (1044.091 us; speedup 1.0000x reference)
//
#include <hip/hip_runtime.h>

// GCN forward: 4x [GEMM -> symmetric-normalized aggregation -> lrelu -> BN(folded)]
// then mean-pool per graph @ Wout.
//
// Key structure:
//  - CSR via counting sort, rank captured in count pass -> placement pass NO atomics.
//  - Layer 1 commuted: A(x@W0) = (Ax)@W0; u bf16 24B rows (2.4MB -> L2-resident,
//    which is why k_spmm9 never shows in top-5: L2-resident gathers are cheap).
//  - dinv folded into GEMM/gather epilogues; BN folded into next GEMM.
//  - R9 fp8 failed accuracy; R10/R11 int8 col-scale gather (order-free int accum).
//  - R4/R12 falsified line-count AND instruction-count models: ~70 cy/edge/CU
//    invariant across bf16/int8, 32/8-lane, dword/dwordx4. Invariant cause:
//    one random row per edge into a table >> 4MB per-XCD L2 (~50% miss to L3).
//  - R13: COLUMN-CHUNKED gather. 4 passes x 32 cols; int8 sub-table N x 32B =
//    3.2MB < 4MB L2 -> gathers become L2 hits. Columns independent end-to-end
//    (self, dequant, BN stats, bias, tw, Wout dot) -> no inter-pass buffer.
//    Same total gather bytes; only rows[] re-streamed 4x (~3us/layer).
//  - cntG via binary search on sorted batch; final layer fuses pool.

#define LRELU(z) ((z) > 0.f ? (z) : 0.01f * (z))

typedef __attribute__((ext_vector_type(8))) short short8;
typedef __attribute__((ext_vector_type(4))) float float4v;

__device__ inline unsigned bf16_rn(float a) {
  unsigned u = __float_as_uint(a);
  return (u + 0x7FFFu + ((u >> 16) & 1u)) >> 16;
}

__device__ inline unsigned pack_bf16x2(float a, float b) {
  return bf16_rn(a) | (bf16_rn(b) << 16);
}

__device__ inline float bf16f(unsigned short s) {
  return __uint_as_float(((unsigned)s) << 16);
}

__device__ inline float4 unpack_bf16x4(uint2 u) {
  float4 r;
  r.x = __uint_as_float(u.x << 16);
  r.y = __uint_as_float(u.x & 0xffff0000u);
  r.z = __uint_as_float(u.y << 16);
  r.w = __uint_as_float(u.y & 0xffff0000u);
  return r;
}

// sign-extend 4 packed int8 lanes of v into int4 accumulator d
__device__ inline void accb(int4& d, unsigned v) {
  d.x += ((int)(v << 24)) >> 24;
  d.y += ((int)(v << 16)) >> 24;
  d.z += ((int)(v << 8)) >> 24;
  d.w += ((int)v) >> 24;
}

// count pass: cnt[col]++ and record each edge's rank within its column.
__global__ __launch_bounds__(256) void k_count(const int* __restrict__ ei,
                                               int* __restrict__ cnt,
                                               int* __restrict__ rank, int E) {
  int i = blockIdx.x * 256 + threadIdx.x;
  if (i < E) rank[i] = atomicAdd(&cnt[ei[E + i]], 1);
}

// block-scan of cnt + dinv fused
__global__ __launch_bounds__(256) void k_scan1(const int* __restrict__ cnt,
                                               int* __restrict__ incl,
                                               int* __restrict__ bsums,
                                               float* __restrict__ dinv, int N) {
  __shared__ int s[256];
  int tid = threadIdx.x;
  int idx = blockIdx.x * 256 + tid;
  int v = (idx < N) ? cnt[idx] : 0;
  if (idx < N) dinv[idx] = rsqrtf((float)(v + 1));
  s[tid] = v;
  __syncthreads();
  for (int off = 1; off < 256; off <<= 1) {
    int t = (tid >= off) ? s[tid - off] : 0;
    __syncthreads();
    s[tid] += t;
    __syncthreads();
  }
  if (idx < N) incl[idx] = s[tid];
  if (tid == 255) bsums[blockIdx.x] = s[255];
}

// nb must be <= 512 (N <= 131072 here: nb = 391)
__global__ __launch_bounds__(512) void k_scan2(const int* __restrict__ bsums,
                                               int* __restrict__ bpref, int nb) {
  __shared__ int s[512];
  int tid = threadIdx.x;
  int v = (tid < nb) ? bsums[tid] : 0;
  s[tid] = v;
  __syncthreads();
  for (int off = 1; off < 512; off <<= 1) {
    int t = (tid >= off) ? s[tid - off] : 0;
    __syncthreads();
    s[tid] += t;
    __syncthreads();
  }
  bpref[tid] = s[tid] - v;  // exclusive prefix of block sums
}

// cntG[g] = #nodes with batch==g, via binary search on the SORTED batch array.
__global__ __launch_bounds__(256) void k_cntg(const int* __restrict__ batch,
                                              float* __restrict__ cntG,
                                              int N, int G) {
  int g = blockIdx.x * 256 + threadIdx.x;
  if (g >= G) return;
  int lo = 0, hi = N;
  while (lo < hi) { int mid = (lo + hi) >> 1; if (batch[mid] < g) lo = mid + 1; else hi = mid; }
  int a = lo;
  hi = N;
  while (lo < hi) { int mid = (lo + hi) >> 1; if (batch[mid] < g + 1) lo = mid + 1; else hi = mid; }
  cntG[g] = (float)(lo - a);
}

// offs computation + u preparation fused: u[v][0:9] = bf16(x[v][0:9]*dinv[v]),
// slot 9 = bf16(dinv[v]), slots 10,11 = 0. 24B rows. Also emits meta=(offs,cnt).
__global__ __launch_bounds__(256) void k_scan3_prep(
    const int* __restrict__ incl, const int* __restrict__ cnt,
    const int* __restrict__ bpref, int* __restrict__ offs,
    int2* __restrict__ meta, const float* __restrict__ x,
    const float* __restrict__ dinv, unsigned* __restrict__ u, int N) {
  int idx = blockIdx.x * 256 + threadIdx.x;
  if (idx >= N) return;
  int c = cnt[idx];
  int off = incl[idx] - c + bpref[blockIdx.x];
  offs[idx] = off;
  meta[idx] = make_int2(off, c);
  float dv = dinv[idx];
  const float* xr = x + (size_t)idx * 9;
  unsigned p0 = pack_bf16x2(xr[0] * dv, xr[1] * dv);
  unsigned p1 = pack_bf16x2(xr[2] * dv, xr[3] * dv);
  unsigned p2 = pack_bf16x2(xr[4] * dv, xr[5] * dv);
  unsigned p3 = pack_bf16x2(xr[6] * dv, xr[7] * dv);
  unsigned p4 = pack_bf16x2(xr[8] * dv, dv);
  uint2* u2 = (uint2*)u;
  u2[(size_t)idx * 3 + 0] = make_uint2(p0, p1);
  u2[(size_t)idx * 3 + 1] = make_uint2(p2, p3);
  u2[(size_t)idx * 3 + 2] = make_uint2(p4, 0u);
}

// CSR placement: NO atomics (offs random read + rank from count pass).
__global__ __launch_bounds__(256) void k_csr(const int* __restrict__ ei,
                                             const int* __restrict__ offs,
                                             const int* __restrict__ rank,
                                             int* __restrict__ rows, int E) {
  int i = blockIdx.x * 256 + threadIdx.x;
  if (i < E) {
    int c = ei[E + i];
    rows[offs[c] + rank[i]] = ei[i];
  }
}

// ax[v] = dinv[v]*(u[v] + sum_in u[row]); lane 9 accumulates sum_in dinv[row]
// and emits dq[v] = (dinv, dinv*(dinv+sd)). 16-lane group per node.
__global__ __launch_bounds__(256) void k_spmm9(
    const unsigned short* __restrict__ u, const int2* __restrict__ meta,
    const int* __restrict__ rows, const float* __restrict__ dinv,
    float* __restrict__ ax, float2* __restrict__ dq, int N) {
  const int t = threadIdx.x;
  const int g = t >> 4;
  const int f = t & 15;
  const int v = blockIdx.x * 16 + g;
  if (v >= N) return;
  const int2 m = meta[v];
  const int st = m.x;
  const int dg = m.y;
  const float dv = dinv[v];
  const bool act = (f < 10);
  float a0 = (f < 9) ? bf16f(u[(unsigned)v * 12u + f]) : 0.f;
  float a1 = 0.f, a2 = 0.f, a3 = 0.f;
  int idx = 0;
  if (f < (dg < 16 ? dg : 16)) idx = rows[st + f];
  for (int b = 0; b < dg; b += 16) {
    int rem = dg - b;
    int mm = rem < 16 ? rem : 16;
    const int cur = idx;
    if (b + 16 < dg) idx = (f < rem - 16) ? rows[st + b + 16 + f] : 0;
    int e = 0;
    for (; e + 8 <= mm; e += 8) {
      int r0 = __shfl(cur, e + 0, 16), r1 = __shfl(cur, e + 1, 16);
      int r2 = __shfl(cur, e + 2, 16), r3 = __shfl(cur, e + 3, 16);
      int r4 = __shfl(cur, e + 4, 16), r5 = __shfl(cur, e + 5, 16);
      int r6 = __shfl(cur, e + 6, 16), r7 = __shfl(cur, e + 7, 16);
      float x0 = 0, x1 = 0, x2 = 0, x3 = 0, x4 = 0, x5 = 0, x6 = 0, x7 = 0;
      if (act) {
        x0 = bf16f(u[(unsigned)r0 * 12u + f]); x1 = bf16f(u[(unsigned)r1 * 12u + f]);
        x2 = bf16f(u[(unsigned)r2 * 12u + f]); x3 = bf16f(u[(unsigned)r3 * 12u + f]);
        x4 = bf16f(u[(unsigned)r4 * 12u + f]); x5 = bf16f(u[(unsigned)r5 * 12u + f]);
        x6 = bf16f(u[(unsigned)r6 * 12u + f]); x7 = bf16f(u[(unsigned)r7 * 12u + f]);
      }
      a0 += x0; a1 += x1; a2 += x2; a3 += x3;
      a0 += x4; a1 += x5; a2 += x6; a3 += x7;
    }
    for (; e + 4 <= mm; e += 4) {
      int r0 = __shfl(cur, e + 0, 16), r1 = __shfl(cur, e + 1, 16);
      int r2 = __shfl(cur, e + 2, 16), r3 = __shfl(cur, e + 3, 16);
      float x0 = 0, x1 = 0, x2 = 0, x3 = 0;
      if (act) {
        x0 = bf16f(u[(unsigned)r0 * 12u + f]); x1 = bf16f(u[(unsigned)r1 * 12u + f]);
        x2 = bf16f(u[(unsigned)r2 * 12u + f]); x3 = bf16f(u[(unsigned)r3 * 12u + f]);
      }
      a0 += x0; a1 += x1; a2 += x2; a3 += x3;
    }
    for (; e < mm; e++) {
      int r = __shfl(cur, e, 16);
      if (act) a0 += bf16f(u[(unsigned)r * 12u + f]);
    }
  }
  float sum = (a0 + a1) + (a2 + a3);
  if (f < 9) {
    ax[(unsigned)v * 12u + f] = sum * dv;
  } else if (f == 9) {
    dq[v] = make_float2(dv, dv * (dv + sum));
  }
}

// h1 = lrelu(ax[v][0:9] @ W0 + b0); writes Abuf (bf16); accumulates fp32 BN stats.
__global__ __launch_bounds__(256) void k_gemm_in(
    const float* __restrict__ ax, const float* __restrict__ W0,
    const float* __restrict__ b0, unsigned short* __restrict__ Abuf,
    float* __restrict__ stats, int N) {
  __shared__ float Wl[9 * 128];
  __shared__ float rs[128], rq[128];
  const int t = threadIdx.x;
  for (int i = t; i < 9 * 128; i += 256) Wl[i] = W0[i];
  if (t < 128) { rs[t] = 0.f; rq[t] = 0.f; }
  __syncthreads();
  const int col = t & 127;
  const int rsub = t >> 7;
  const int base = blockIdx.x * 16;
  const float bc = b0[col];
  float ls = 0.f, lq = 0.f;
  for (int it = 0; it < 8; it++) {
    int row = base + it * 2 + rsub;
    if (row < N) {
      const float* ar = ax + (size_t)row * 12;
      float acc = bc;
#pragma unroll
      for (int k = 0; k < 9; k++) acc += ar[k] * Wl[k * 128 + col];
      float a = LRELU(acc);
      Abuf[(size_t)row * 128 + col] = (unsigned short)bf16_rn(a);
      ls += a;
      lq += a * a;
    }
  }
  atomicAdd(&rs[col], ls);
  atomicAdd(&rq[col], lq);
  __syncthreads();
  if (t < 128) {
    atomicAdd(&stats[t], rs[t]);
    atomicAdd(&stats[128 + t], rq[t]);
  }
}

// bf16 MFMA GEMM: L[v][:] = bf16((A[v][:] @ Wf) * dinv[v]).
// Block: 64 rows, 4 waves x (16 rows x 128 cols). Wb pre-swizzled B-frag order.
// Also reduces per-column absmax of L into colmaxU.
__global__ __launch_bounds__(256) void k_gemm_mfma(
    const unsigned short* __restrict__ Ab, const uint4* __restrict__ Wb,
    const float* __restrict__ dinv, unsigned short* __restrict__ Lb,
    unsigned* __restrict__ colmaxU, int N) {
  __shared__ uint4 Bl[2048];               // 32 KB: all B fragments
  __shared__ unsigned short Dl[4 * 2048];  // 16 KB: per-wave D staging
  __shared__ float dvs[64];
  __shared__ unsigned cmx[128];
  const int t = threadIdx.x;
  const int row0 = blockIdx.x * 64;
#pragma unroll
  for (int i = 0; i < 8; i++) Bl[t + i * 256] = Wb[t + i * 256];
  if (t < 128) cmx[t] = 0u;
  if (t < 64) {
    int r = row0 + t;
    dvs[t] = (r < N) ? dinv[r] : 0.f;
  }
  __syncthreads();
  const int w = t >> 6;
  const int lane = t & 63;
  const int m = lane & 15;
  const int quad = lane >> 4;
  const int rowA = min(row0 + w * 16 + m, N - 1);
  const uint4* Arow = (const uint4*)(Ab + (size_t)rowA * 128);
  uint4 a[4];
#pragma unroll
  for (int kt = 0; kt < 4; kt++) a[kt] = Arow[kt * 4 + quad];
  float4v acc[8];
#pragma unroll
  for (int nt = 0; nt < 8; nt++) acc[nt] = (float4v)0.0f;
#pragma unroll
  for (int nt = 0; nt < 8; nt++) {
#pragma unroll
    for (int kt = 0; kt < 4; kt++) {
      uint4 b = Bl[((kt * 8 + nt) * 4 + quad) * 16 + m];
      acc[nt] = __builtin_amdgcn_mfma_f32_16x16x32_bf16(
          *(short8*)&a[kt], *(short8*)&b, acc[nt], 0, 0, 0);
    }
  }
  unsigned short* Dw = Dl + w * 2048;
  float cm8[8];
#pragma unroll
  for (int nt = 0; nt < 8; nt++) cm8[nt] = 0.f;
#pragma unroll
  for (int r = 0; r < 4; r++) {
    float dv = dvs[w * 16 + quad * 4 + r];
#pragma unroll
    for (int nt = 0; nt < 8; nt++) {
      float fv = acc[nt][r] * dv;
      Dw[(quad * 4 + r) * 128 + nt * 16 + m] = (unsigned short)bf16_rn(fv);
      cm8[nt] = fmaxf(cm8[nt], fabsf(fv));
    }
  }
#pragma unroll
  for (int nt = 0; nt < 8; nt++)
    atomicMax(&cmx[nt * 16 + m], __float_as_uint(cm8[nt]));
  __syncthreads();
  const uint4* Dw4 = (const uint4*)Dw;
#pragma unroll
  for (int p = 0; p < 4; p++) {
    int row = row0 + w * 16 + p * 4 + (lane >> 4);
    if (row < N) {
      ((uint4*)(Lb + (size_t)row * 128))[lane & 15] = Dw4[p * 64 + lane];
    }
  }
  if (t < 128) atomicMax(&colmaxU[t], cmx[t]);
}

// Quantize Lb (bf16, 256B rows) -> L8 CHUNKED int8: chunk c holds cols
// [32c,32c+32) as N x 32B. Sub-table = 3.2MB -> L2-resident during pass c.
__global__ __launch_bounds__(256) void k_quant(
    const unsigned short* __restrict__ Lb, const unsigned* __restrict__ cmU,
    unsigned* __restrict__ L8, int N, int N4) {
  __shared__ float invS[128];
  const int t = threadIdx.x;
  if (t < 128) {
    float cm = __uint_as_float(cmU[t]);
    invS[t] = cm > 0.f ? 127.f / cm : 0.f;
  }
  __syncthreads();
  int idx = blockIdx.x * 256 + t;
  if (idx >= N4) return;
  const int row = idx >> 2;
  const int seg = idx & 3;  // == column chunk
  const uint2* src = (const uint2*)(Lb + (size_t)row * 128 + seg * 32);
  const float* inv = invS + seg * 32;
  unsigned d[8];
#pragma unroll
  for (int j = 0; j < 8; j++) {
    float4 f = unpack_bf16x4(src[j]);
    int q0 = __float2int_rn(f.x * inv[j * 4 + 0]);
    int q1 = __float2int_rn(f.y * inv[j * 4 + 1]);
    int q2 = __float2int_rn(f.z * inv[j * 4 + 2]);
    int q3 = __float2int_rn(f.w * inv[j * 4 + 3]);
    q0 = max(-127, min(127, q0));
    q1 = max(-127, min(127, q1));
    q2 = max(-127, min(127, q2));
    q3 = max(-127, min(127, q3));
    d[j] = (unsigned)(q0 & 255) | ((unsigned)(q1 & 255) << 8) |
           ((unsigned)(q2 & 255) << 16) | ((unsigned)(q3 & 255) << 24);
  }
  // chunked write: dword j of row's chunk = cols seg*32 + 4j .. +3
  uint4* dst = (uint4*)(L8 + (size_t)seg * N * 8 + (size_t)row * 8);
  dst[0] = make_uint4(d[0], d[1], d[2], d[3]);
  dst[1] = make_uint4(d[4], d[5], d[6], d[7]);
}

// Column-chunked SpMM pass: full pipeline for 32 columns [32*chunk, +32).
// 8-lane clusters; lane c owns 4 cols (one dword of the 32B sub-row); cluster
// handles 2 sequential nodes. Gather target = 3.2MB L2-resident sub-table.
// Dequant: accF = self + (float)iacc * (colmax/127). Columns independent ->
// no inter-pass state. MODE 0: write Aout cols + BN stats (chunk's 32 slots).
// MODE 1: partial dot(a[cols], Wout[cols]) -> run-aggregated pacc atomics.
template <int MODE>
__global__ __launch_bounds__(256) void k_spmmc(
    const unsigned* __restrict__ Lb, const unsigned* __restrict__ L8,
    const unsigned* __restrict__ cmU, const int2* __restrict__ meta,
    const int* __restrict__ rows, const float2* __restrict__ dq,
    const float* __restrict__ tw, const float* __restrict__ bias,
    unsigned short* __restrict__ Aout, float* __restrict__ stats,
    const float* __restrict__ wout, const int* __restrict__ batch,
    float* __restrict__ pacc, int N, int chunk) {
  const int t = threadIdx.x;
  const int c = t & 7;    // lane in cluster: owns cols chunk*32 + c*4 .. +3
  const int cl = t >> 3;  // cluster 0..31
  const int q4 = (chunk << 3) + c;  // float4 index of this lane's cols
  const float4 t4 = ((const float4*)tw)[q4];
  const float4 b4 = ((const float4*)bias)[q4];
  const float4 cm4 = ((const float4*)(const void*)cmU)[q4];
  const float ksc = 1.f / 127.f;
  const float4 s4 =
      make_float4(cm4.x * ksc, cm4.y * ksc, cm4.z * ksc, cm4.w * ksc);
  float4 wo4 = make_float4(0.f, 0.f, 0.f, 0.f);
  if (MODE == 1) wo4 = ((const float4*)wout)[q4];
  __shared__ float rs[32], rq[32];
  __shared__ float psum[64];
  __shared__ int pb[64];
  if (MODE == 0) {
    if (t < 32) { rs[t] = 0.f; rq[t] = 0.f; }
  } else {
    if (t < 64) pb[t] = -1;
  }
  __syncthreads();
  const unsigned* __restrict__ sub = L8 + (size_t)chunk * N * 8;
  const uint2* __restrict__ Lb2 = (const uint2*)Lb;
  const int vb = blockIdx.x * 64 + cl * 2;
  float4 ls = make_float4(0.f, 0.f, 0.f, 0.f), lq = ls;
  for (int n = 0; n < 2; n++) {
    const int v = vb + n;
    const bool ok = v < N;
    const int vv = ok ? v : N - 1;
    const int2 m = meta[vv];
    const int st = m.x;
    const int dg = ok ? m.y : 0;
    const float2 dv = dq[vv];
    // self sub-row: 8B bf16 = this lane's 4 cols (Lb row = 32 uint2)
    uint2 selfu = Lb2[(size_t)vv * 32 + (unsigned)q4];
    int bt = 0;
    if (MODE == 1) bt = batch[vv];
    // batch-0 indices in flight before gather
    int idxv = 0;
    if (c < (dg < 8 ? dg : 8)) idxv = rows[st + c];
    int4 s = make_int4(0, 0, 0, 0);
    for (int b = 0; b < dg; b += 8) {
      int rem = dg - b;
      int mm = rem < 8 ? rem : 8;
      const int cur = idxv;
      if (b + 8 < dg) idxv = (c < rem - 8) ? rows[st + b + 8 + c] : 0;
      if (mm == 8) {
        int r0 = __shfl(cur, 0, 8), r1 = __shfl(cur, 1, 8);
        int r2 = __shfl(cur, 2, 8), r3 = __shfl(cur, 3, 8);
        int r4 = __shfl(cur, 4, 8), r5 = __shfl(cur, 5, 8);
        int r6 = __shfl(cur, 6, 8), r7 = __shfl(cur, 7, 8);
        unsigned w0 = sub[((size_t)(unsigned)r0 << 3) + c];
        unsigned w1 = sub[((size_t)(unsigned)r1 << 3) + c];
        unsigned w2 = sub[((size_t)(unsigned)r2 << 3) + c];
        unsigned w3 = sub[((size_t)(unsigned)r3 << 3) + c];
        unsigned w4 = sub[((size_t)(unsigned)r4 << 3) + c];
        unsigned w5 = sub[((size_t)(unsigned)r5 << 3) + c];
        unsigned w6 = sub[((size_t)(unsigned)r6 << 3) + c];
        unsigned w7 = sub[((size_t)(unsigned)r7 << 3) + c];
        accb(s, w0); accb(s, w1); accb(s, w2); accb(s, w3);
        accb(s, w4); accb(s, w5); accb(s, w6); accb(s, w7);
      } else {
        for (int e = 0; e < mm; e++) {
          int r = __shfl(cur, e, 8);
          accb(s, sub[((size_t)(unsigned)r << 3) + c]);
        }
      }
    }
    float4 sf = unpack_bf16x4(selfu);
    float4 accf;
    accf.x = sf.x + (float)s.x * s4.x;
    accf.y = sf.y + (float)s.y * s4.y;
    accf.z = sf.z + (float)s.z * s4.z;
    accf.w = sf.w + (float)s.w * s4.w;
    float4 a;
    a.x = LRELU(dv.x * accf.x + dv.y * t4.x + b4.x);
    a.y = LRELU(dv.x * accf.y + dv.y * t4.y + b4.y);
    a.z = LRELU(dv.x * accf.z + dv.y * t4.z + b4.z);
    a.w = LRELU(dv.x * accf.w + dv.y * t4.w + b4.w);
    if (MODE == 0) {
      if (ok) {
        uint2 p;
        p.x = pack_bf16x2(a.x, a.y);
        p.y = pack_bf16x2(a.z, a.w);
        ((uint2*)Aout)[(size_t)v * 32 + (unsigned)q4] = p;
        ls.x += a.x; ls.y += a.y; ls.z += a.z; ls.w += a.w;
        lq.x += a.x * a.x; lq.y += a.y * a.y;
        lq.z += a.z * a.z; lq.w += a.w * a.w;
      }
    } else {
      float sdot = a.x * wo4.x + a.y * wo4.y + a.z * wo4.z + a.w * wo4.w;
      sdot += __shfl_down(sdot, 4, 8);
      sdot += __shfl_down(sdot, 2, 8);
      sdot += __shfl_down(sdot, 1, 8);
      if (c == 0 && ok) {
        psum[cl * 2 + n] = sdot;
        pb[cl * 2 + n] = bt;
      }
    }
  }
  if (MODE == 0) {
    const int f0 = c * 4;
    atomicAdd(&rs[f0 + 0], ls.x); atomicAdd(&rs[f0 + 1], ls.y);
    atomicAdd(&rs[f0 + 2], ls.z); atomicAdd(&rs[f0 + 3], ls.w);
    atomicAdd(&rq[f0 + 0], lq.x); atomicAdd(&rq[f0 + 1], lq.y);
    atomicAdd(&rq[f0 + 2], lq.z); atomicAdd(&rq[f0 + 3], lq.w);
    __syncthreads();
    if (t < 32) {
      atomicAdd(&stats[chunk * 32 + t], rs[t]);
      atomicAdd(&stats[128 + chunk * 32 + t], rq[t]);
    }
  } else {
    __syncthreads();
    if (t < 64) {
      int b = pb[t];
      if (b >= 0 && (t == 0 || pb[t - 1] != b)) {
        float sr = psum[t];
        for (int j = t + 1; j < 64 && pb[j] == b; j++) sr += psum[j];
        atomicAdd(&pacc[b], sr);
      }
    }
  }
}

// Fold BN affine into next layer's weights (parallel: 8 blocks x 16 W-rows).
// Emits bf16 Wb in MFMA B-frag order; tw accumulated atomically (pre-zeroed).
__global__ __launch_bounds__(128) void k_fold(const float* __restrict__ stats,
                                              const float* __restrict__ g,
                                              const float* __restrict__ be,
                                              const float* __restrict__ W,
                                              unsigned short* __restrict__ Wb,
                                              float* __restrict__ tw, float invN) {
  const int j = threadIdx.x;
  const int i0 = blockIdx.x * 16;
  const int nt = j >> 4;
  const int n = j & 15;
  float acc = 0.f;
#pragma unroll
  for (int ii = 0; ii < 16; ii++) {
    int i = i0 + ii;
    float m = stats[i] * invN;
    float var = stats[128 + i] * invN - m * m;
    float si = g[i] * rsqrtf(var + 1e-5f);
    float ti = be[i] - m * si;
    float w = W[i * 128 + j];
    acc += ti * w;
    int kt = i >> 5, quad = (i >> 3) & 3, jj = i & 7;
    Wb[((((kt * 8 + nt) * 4 + quad) * 16 + n) << 3) + jj] =
        (unsigned short)bf16_rn(si * w);
  }
  atomicAdd(&tw[j], acc);
}

__global__ __launch_bounds__(256) void k_out(const float* __restrict__ pacc,
                                             const float* __restrict__ cntG,
                                             const float* __restrict__ bout,
                                             float* __restrict__ out, int G) {
  int i = blockIdx.x * 256 + threadIdx.x;
  if (i < G) out[i] = pacc[i] / fmaxf(cntG[i], 1.0f) + bout[0];
}

extern "C" void kernel_launch(void* const* d_in, const int* in_sizes, int n_in,
                              void* d_out, int out_size, void* d_ws, size_t ws_size,
                              hipStream_t stream) {
  const float* x    = (const float*)d_in[0];
  const int*   ei   = (const int*)d_in[1];
  const int*   batch= (const int*)d_in[2];
  const float* W0   = (const float*)d_in[3];
  const float* b0   = (const float*)d_in[4];
  const float* W1   = (const float*)d_in[5];
  const float* b1   = (const float*)d_in[6];
  const float* W2   = (const float*)d_in[7];
  const float* b2   = (const float*)d_in[8];
  const float* W3   = (const float*)d_in[9];
  const float* b3   = (const float*)d_in[10];
  const float* g1   = (const float*)d_in[11];
  const float* be1  = (const float*)d_in[12];
  const float* g2   = (const float*)d_in[13];
  const float* be2  = (const float*)d_in[14];
  const float* g3   = (const float*)d_in[15];
  const float* be3  = (const float*)d_in[16];
  const float* Wout = (const float*)d_in[17];
  const float* bout = (const float*)d_in[18];
  float* out = (float*)d_out;

  const int N = in_sizes[0] / 9;
  const int E = in_sizes[1] / 2;
  const int G = out_size;

  char* w = (char*)d_ws;
  auto alloc = [&](size_t bytes) -> void* {
    void* p = (void*)w;
    w += (bytes + 255) & ~(size_t)255;
    return p;
  };
  // ---- zeroed region (ONE memset) ----
  char* zbase = w;
  int*   cnt    = (int*)alloc((size_t)N * 4);
  float* pacc   = (float*)alloc((size_t)G * 4);
  float* stats  = (float*)alloc(3 * 256 * 4);
  float* tw3    = (float*)alloc(3 * 128 * 4);
  unsigned* cmU3 = (unsigned*)alloc(3 * 128 * 4);  // per-layer col absmax (bits)
  size_t zsize = (size_t)(w - zbase);
  // ---- non-zeroed ----
  int*   offs   = (int*)alloc((size_t)N * 4);
  int*   incl   = (int*)alloc((size_t)N * 4);
  int*   bsums  = (int*)alloc(512 * 4);
  int*   bpref  = (int*)alloc(512 * 4);
  float* dinv   = (float*)alloc((size_t)N * 4);
  float2* dq    = (float2*)alloc((size_t)N * 8);
  int2*  meta   = (int2*)alloc((size_t)N * 8);
  float* cntG   = (float*)alloc((size_t)G * 4);
  int*   rank   = (int*)alloc((size_t)E * 4);
  int*   rows   = (int*)alloc((size_t)E * 4);
  unsigned short* Wb = (unsigned short*)alloc(128 * 128 * 2);  // bf16 B-frag layout
  unsigned* u   = (unsigned*)alloc((size_t)N * 12 * 2);        // bf16, 24B rows
  float* ax     = (float*)alloc((size_t)N * 12 * 4);
  unsigned* Lb  = (unsigned*)alloc((size_t)N * 128 * 2);       // bf16 rows, 256B
  unsigned* L8  = (unsigned*)alloc((size_t)N * 128);  // int8, 4 chunks x N x 32B
  unsigned short* Abuf = (unsigned short*)alloc((size_t)N * 128 * 2);  // bf16 acts

  hipMemsetAsync(zbase, 0, zsize, stream);

  const int eb  = (E + 255) / 256;
  const int nbN = (N + 255) / 256;  // also the scan block count (must be <= 512)
  const int sb  = (N + 15) / 16;    // spmm9 / gemm_in blocks
  const int sbC = (N + 63) / 64;    // k_spmmc blocks (32 clusters x 2 nodes)
  const int mb  = (N + 63) / 64;    // mfma gemm blocks
  const int qb  = (N * 4 + 255) / 256;  // quant blocks
  const float invN = 1.0f / (float)N;
  float* twA = tw3;
  float* twB = tw3 + 128;
  float* twC = tw3 + 256;
  unsigned* cmA = cmU3;
  unsigned* cmB = cmU3 + 128;
  unsigned* cmC = cmU3 + 256;

  // --- graph preprocessing ---
  k_count<<<eb, 256, 0, stream>>>(ei, cnt, rank, E);
  k_scan1<<<nbN, 256, 0, stream>>>(cnt, incl, bsums, dinv, N);
  k_scan2<<<1, 512, 0, stream>>>(bsums, bpref, nbN);
  k_scan3_prep<<<nbN, 256, 0, stream>>>(incl, cnt, bpref, offs, meta, x, dinv, u, N);
  k_csr<<<eb, 256, 0, stream>>>(ei, offs, rank, rows, E);
  k_cntg<<<(G + 255) / 256, 256, 0, stream>>>(batch, cntG, N, G);

  // --- layer 1: aggregate 9-dim input first (A x) @ W0; also emits dq ---
  k_spmm9<<<sb, 256, 0, stream>>>((const unsigned short*)u, meta, rows,
                                  dinv, ax, dq, N);
  k_gemm_in<<<sb, 256, 0, stream>>>(ax, W0, b0, Abuf, stats, N);
  // --- layer 2 ---
  k_fold<<<8, 128, 0, stream>>>(stats, g1, be1, W1, Wb, twA, invN);
  k_gemm_mfma<<<mb, 256, 0, stream>>>(Abuf, (const uint4*)Wb, dinv,
                                      (unsigned short*)Lb, cmA, N);
  k_quant<<<qb, 256, 0, stream>>>((const unsigned short*)Lb, cmA, L8, N, N * 4);
  for (int ch = 0; ch < 4; ch++)
    k_spmmc<0><<<sbC, 256, 0, stream>>>(Lb, L8, cmA, meta, rows, dq, twA, b1,
                                        Abuf, stats + 256, nullptr, nullptr,
                                        nullptr, N, ch);
  // --- layer 3 ---
  k_fold<<<8, 128, 0, stream>>>(stats + 256, g2, be2, W2, Wb, twB, invN);
  k_gemm_mfma<<<mb, 256, 0, stream>>>(Abuf, (const uint4*)Wb, dinv,
                                      (unsigned short*)Lb, cmB, N);
  k_quant<<<qb, 256, 0, stream>>>((const unsigned short*)Lb, cmB, L8, N, N * 4);
  for (int ch = 0; ch < 4; ch++)
    k_spmmc<0><<<sbC, 256, 0, stream>>>(Lb, L8, cmB, meta, rows, dq, twB, b2,
                                        Abuf, stats + 512, nullptr, nullptr,
                                        nullptr, N, ch);
  // --- layer 4 (+ fused pool @ Wout) ---
  k_fold<<<8, 128, 0, stream>>>(stats + 512, g3, be3, W3, Wb, twC, invN);
  k_gemm_mfma<<<mb, 256, 0, stream>>>(Abuf, (const uint4*)Wb, dinv,
                                      (unsigned short*)Lb, cmC, N);
  k_quant<<<qb, 256, 0, stream>>>((const unsigned short*)Lb, cmC, L8, N, N * 4);
  for (int ch = 0; ch < 4; ch++)
    k_spmmc<1><<<sbC, 256, 0, stream>>>(Lb, L8, cmC, meta, rows, dq, twC, b3,
                                        nullptr, nullptr, Wout, batch, pacc,
                                        N, ch);
  k_out<<<(G + 255) / 256, 256, 0, stream>>>(pacc, cntG, bout, out, G);
}

// Round 7
// 724.579 us; speedup vs baseline: 1.4410x; 1.4410x over previous
//
#include <hip/hip_runtime.h>

// GCN forward: 4x [GEMM -> symmetric-normalized aggregation -> lrelu -> BN(folded)]
// then mean-pool per graph @ Wout.
//
// Key structure:
//  - CSR via counting sort, rank captured in count pass -> placement pass NO atomics.
//  - Layer 1 commuted: A(x@W0) = (Ax)@W0; u bf16 24B rows.
//  - dinv folded into GEMM/gather epilogues; BN folded into next GEMM.
//  - R9 fp8 failed accuracy; R10/R11 int8 col-scale gather (order-free int accum).
//  - R4/R12/R13 falsified line-count, instruction-count, AND L2-residency models
//    for the ~180us/layer wall (int8 bytes/2 -> 0 delta; 4x fewer scatter instrs
//    -> regression; 3.2MB L2-resident chunks -> regression).
//  - R14 theory: the wall is the STATS ATOMIC STORM - 6250 blocks x 256 global
//    atomicAdds into a 1KB region (1.6M device atomics serializing at one L2).
//    Evidence: k_gemm_in (no gather, no traffic, 60% occ) = 164us with the same
//    storm; every gather-side fix was a null result.
//    Fix: per-block partials part[block][256] (coalesced stores, NO atomics) +
//    k_redstats reduction (64 blocks, 6.4MB stream, 16K atomics, ~5us).
//    k_spmm/k_quant reverted to R4 winners. MODE0 vs MODE1 durations in next
//    counters disambiguate atomic-wall vs gather-wall.
//  - cntG via binary search on sorted batch; final layer fuses pool.

#define LRELU(z) ((z) > 0.f ? (z) : 0.01f * (z))

typedef __attribute__((ext_vector_type(8))) short short8;
typedef __attribute__((ext_vector_type(4))) float float4v;

__device__ inline unsigned bf16_rn(float a) {
  unsigned u = __float_as_uint(a);
  return (u + 0x7FFFu + ((u >> 16) & 1u)) >> 16;
}

__device__ inline unsigned pack_bf16x2(float a, float b) {
  return bf16_rn(a) | (bf16_rn(b) << 16);
}

__device__ inline float bf16f(unsigned short s) {
  return __uint_as_float(((unsigned)s) << 16);
}

__device__ inline float4 unpack_bf16x4(uint2 u) {
  float4 r;
  r.x = __uint_as_float(u.x << 16);
  r.y = __uint_as_float(u.x & 0xffff0000u);
  r.z = __uint_as_float(u.y << 16);
  r.w = __uint_as_float(u.y & 0xffff0000u);
  return r;
}

// sign-extend 4 packed int8 lanes of v into int4 accumulator d
__device__ inline void accb(int4& d, unsigned v) {
  d.x += ((int)(v << 24)) >> 24;
  d.y += ((int)(v << 16)) >> 24;
  d.z += ((int)(v << 8)) >> 24;
  d.w += ((int)v) >> 24;
}

// count pass: cnt[col]++ and record each edge's rank within its column.
__global__ __launch_bounds__(256) void k_count(const int* __restrict__ ei,
                                               int* __restrict__ cnt,
                                               int* __restrict__ rank, int E) {
  int i = blockIdx.x * 256 + threadIdx.x;
  if (i < E) rank[i] = atomicAdd(&cnt[ei[E + i]], 1);
}

// block-scan of cnt + dinv fused
__global__ __launch_bounds__(256) void k_scan1(const int* __restrict__ cnt,
                                               int* __restrict__ incl,
                                               int* __restrict__ bsums,
                                               float* __restrict__ dinv, int N) {
  __shared__ int s[256];
  int tid = threadIdx.x;
  int idx = blockIdx.x * 256 + tid;
  int v = (idx < N) ? cnt[idx] : 0;
  if (idx < N) dinv[idx] = rsqrtf((float)(v + 1));
  s[tid] = v;
  __syncthreads();
  for (int off = 1; off < 256; off <<= 1) {
    int t = (tid >= off) ? s[tid - off] : 0;
    __syncthreads();
    s[tid] += t;
    __syncthreads();
  }
  if (idx < N) incl[idx] = s[tid];
  if (tid == 255) bsums[blockIdx.x] = s[255];
}

// nb must be <= 512 (N <= 131072 here: nb = 391)
__global__ __launch_bounds__(512) void k_scan2(const int* __restrict__ bsums,
                                               int* __restrict__ bpref, int nb) {
  __shared__ int s[512];
  int tid = threadIdx.x;
  int v = (tid < nb) ? bsums[tid] : 0;
  s[tid] = v;
  __syncthreads();
  for (int off = 1; off < 512; off <<= 1) {
    int t = (tid >= off) ? s[tid - off] : 0;
    __syncthreads();
    s[tid] += t;
    __syncthreads();
  }
  bpref[tid] = s[tid] - v;  // exclusive prefix of block sums
}

// cntG[g] = #nodes with batch==g, via binary search on the SORTED batch array.
__global__ __launch_bounds__(256) void k_cntg(const int* __restrict__ batch,
                                              float* __restrict__ cntG,
                                              int N, int G) {
  int g = blockIdx.x * 256 + threadIdx.x;
  if (g >= G) return;
  int lo = 0, hi = N;
  while (lo < hi) { int mid = (lo + hi) >> 1; if (batch[mid] < g) lo = mid + 1; else hi = mid; }
  int a = lo;
  hi = N;
  while (lo < hi) { int mid = (lo + hi) >> 1; if (batch[mid] < g + 1) lo = mid + 1; else hi = mid; }
  cntG[g] = (float)(lo - a);
}

// offs computation + u preparation fused: u[v][0:9] = bf16(x[v][0:9]*dinv[v]),
// slot 9 = bf16(dinv[v]), slots 10,11 = 0. 24B rows. Also emits meta=(offs,cnt).
__global__ __launch_bounds__(256) void k_scan3_prep(
    const int* __restrict__ incl, const int* __restrict__ cnt,
    const int* __restrict__ bpref, int* __restrict__ offs,
    int2* __restrict__ meta, const float* __restrict__ x,
    const float* __restrict__ dinv, unsigned* __restrict__ u, int N) {
  int idx = blockIdx.x * 256 + threadIdx.x;
  if (idx >= N) return;
  int c = cnt[idx];
  int off = incl[idx] - c + bpref[blockIdx.x];
  offs[idx] = off;
  meta[idx] = make_int2(off, c);
  float dv = dinv[idx];
  const float* xr = x + (size_t)idx * 9;
  unsigned p0 = pack_bf16x2(xr[0] * dv, xr[1] * dv);
  unsigned p1 = pack_bf16x2(xr[2] * dv, xr[3] * dv);
  unsigned p2 = pack_bf16x2(xr[4] * dv, xr[5] * dv);
  unsigned p3 = pack_bf16x2(xr[6] * dv, xr[7] * dv);
  unsigned p4 = pack_bf16x2(xr[8] * dv, dv);
  uint2* u2 = (uint2*)u;
  u2[(size_t)idx * 3 + 0] = make_uint2(p0, p1);
  u2[(size_t)idx * 3 + 1] = make_uint2(p2, p3);
  u2[(size_t)idx * 3 + 2] = make_uint2(p4, 0u);
}

// CSR placement: NO atomics (offs random read + rank from count pass).
__global__ __launch_bounds__(256) void k_csr(const int* __restrict__ ei,
                                             const int* __restrict__ offs,
                                             const int* __restrict__ rank,
                                             int* __restrict__ rows, int E) {
  int i = blockIdx.x * 256 + threadIdx.x;
  if (i < E) {
    int c = ei[E + i];
    rows[offs[c] + rank[i]] = ei[i];
  }
}

// ax[v] = dinv[v]*(u[v] + sum_in u[row]); lane 9 accumulates sum_in dinv[row]
// and emits dq[v] = (dinv, dinv*(dinv+sd)). 16-lane group per node.
__global__ __launch_bounds__(256) void k_spmm9(
    const unsigned short* __restrict__ u, const int2* __restrict__ meta,
    const int* __restrict__ rows, const float* __restrict__ dinv,
    float* __restrict__ ax, float2* __restrict__ dq, int N) {
  const int t = threadIdx.x;
  const int g = t >> 4;
  const int f = t & 15;
  const int v = blockIdx.x * 16 + g;
  if (v >= N) return;
  const int2 m = meta[v];
  const int st = m.x;
  const int dg = m.y;
  const float dv = dinv[v];
  const bool act = (f < 10);
  float a0 = (f < 9) ? bf16f(u[(unsigned)v * 12u + f]) : 0.f;
  float a1 = 0.f, a2 = 0.f, a3 = 0.f;
  int idx = 0;
  if (f < (dg < 16 ? dg : 16)) idx = rows[st + f];
  for (int b = 0; b < dg; b += 16) {
    int rem = dg - b;
    int mm = rem < 16 ? rem : 16;
    const int cur = idx;
    if (b + 16 < dg) idx = (f < rem - 16) ? rows[st + b + 16 + f] : 0;
    int e = 0;
    for (; e + 8 <= mm; e += 8) {
      int r0 = __shfl(cur, e + 0, 16), r1 = __shfl(cur, e + 1, 16);
      int r2 = __shfl(cur, e + 2, 16), r3 = __shfl(cur, e + 3, 16);
      int r4 = __shfl(cur, e + 4, 16), r5 = __shfl(cur, e + 5, 16);
      int r6 = __shfl(cur, e + 6, 16), r7 = __shfl(cur, e + 7, 16);
      float x0 = 0, x1 = 0, x2 = 0, x3 = 0, x4 = 0, x5 = 0, x6 = 0, x7 = 0;
      if (act) {
        x0 = bf16f(u[(unsigned)r0 * 12u + f]); x1 = bf16f(u[(unsigned)r1 * 12u + f]);
        x2 = bf16f(u[(unsigned)r2 * 12u + f]); x3 = bf16f(u[(unsigned)r3 * 12u + f]);
        x4 = bf16f(u[(unsigned)r4 * 12u + f]); x5 = bf16f(u[(unsigned)r5 * 12u + f]);
        x6 = bf16f(u[(unsigned)r6 * 12u + f]); x7 = bf16f(u[(unsigned)r7 * 12u + f]);
      }
      a0 += x0; a1 += x1; a2 += x2; a3 += x3;
      a0 += x4; a1 += x5; a2 += x6; a3 += x7;
    }
    for (; e + 4 <= mm; e += 4) {
      int r0 = __shfl(cur, e + 0, 16), r1 = __shfl(cur, e + 1, 16);
      int r2 = __shfl(cur, e + 2, 16), r3 = __shfl(cur, e + 3, 16);
      float x0 = 0, x1 = 0, x2 = 0, x3 = 0;
      if (act) {
        x0 = bf16f(u[(unsigned)r0 * 12u + f]); x1 = bf16f(u[(unsigned)r1 * 12u + f]);
        x2 = bf16f(u[(unsigned)r2 * 12u + f]); x3 = bf16f(u[(unsigned)r3 * 12u + f]);
      }
      a0 += x0; a1 += x1; a2 += x2; a3 += x3;
    }
    for (; e < mm; e++) {
      int r = __shfl(cur, e, 16);
      if (act) a0 += bf16f(u[(unsigned)r * 12u + f]);
    }
  }
  float sum = (a0 + a1) + (a2 + a3);
  if (f < 9) {
    ax[(unsigned)v * 12u + f] = sum * dv;
  } else if (f == 9) {
    dq[v] = make_float2(dv, dv * (dv + sum));
  }
}

// h1 = lrelu(ax[v][0:9] @ W0 + b0); writes Abuf (bf16); per-block BN partials
// to part[block][256] (NO global atomics - R14).
__global__ __launch_bounds__(256) void k_gemm_in(
    const float* __restrict__ ax, const float* __restrict__ W0,
    const float* __restrict__ b0, unsigned short* __restrict__ Abuf,
    float* __restrict__ part, int N) {
  __shared__ float Wl[9 * 128];
  __shared__ float rs[128], rq[128];
  const int t = threadIdx.x;
  for (int i = t; i < 9 * 128; i += 256) Wl[i] = W0[i];
  if (t < 128) { rs[t] = 0.f; rq[t] = 0.f; }
  __syncthreads();
  const int col = t & 127;
  const int rsub = t >> 7;
  const int base = blockIdx.x * 16;
  const float bc = b0[col];
  float ls = 0.f, lq = 0.f;
  for (int it = 0; it < 8; it++) {
    int row = base + it * 2 + rsub;
    if (row < N) {
      const float* ar = ax + (size_t)row * 12;
      float acc = bc;
#pragma unroll
      for (int k = 0; k < 9; k++) acc += ar[k] * Wl[k * 128 + col];
      float a = LRELU(acc);
      Abuf[(size_t)row * 128 + col] = (unsigned short)bf16_rn(a);
      ls += a;
      lq += a * a;
    }
  }
  atomicAdd(&rs[col], ls);
  atomicAdd(&rq[col], lq);
  __syncthreads();
  if (t < 128) {
    float* pr = part + (size_t)blockIdx.x * 256;
    pr[t] = rs[t];
    pr[128 + t] = rq[t];
  }
}

// Reduce per-block partials part[nrows][256] into stats[256] (few atomics).
__global__ __launch_bounds__(256) void k_redstats(const float* __restrict__ part,
                                                  float* __restrict__ stats,
                                                  int nrows) {
  const int t = threadIdx.x;
  float s = 0.f;
  for (int r = blockIdx.x; r < nrows; r += gridDim.x)
    s += part[(size_t)r * 256 + t];
  atomicAdd(&stats[t], s);
}

// bf16 MFMA GEMM: L[v][:] = bf16((A[v][:] @ Wf) * dinv[v]).
// Block: 64 rows, 4 waves x (16 rows x 128 cols). Wb pre-swizzled B-frag order.
// Also reduces per-column absmax of L into colmaxU.
__global__ __launch_bounds__(256) void k_gemm_mfma(
    const unsigned short* __restrict__ Ab, const uint4* __restrict__ Wb,
    const float* __restrict__ dinv, unsigned short* __restrict__ Lb,
    unsigned* __restrict__ colmaxU, int N) {
  __shared__ uint4 Bl[2048];               // 32 KB: all B fragments
  __shared__ unsigned short Dl[4 * 2048];  // 16 KB: per-wave D staging
  __shared__ float dvs[64];
  __shared__ unsigned cmx[128];
  const int t = threadIdx.x;
  const int row0 = blockIdx.x * 64;
#pragma unroll
  for (int i = 0; i < 8; i++) Bl[t + i * 256] = Wb[t + i * 256];
  if (t < 128) cmx[t] = 0u;
  if (t < 64) {
    int r = row0 + t;
    dvs[t] = (r < N) ? dinv[r] : 0.f;
  }
  __syncthreads();
  const int w = t >> 6;
  const int lane = t & 63;
  const int m = lane & 15;
  const int quad = lane >> 4;
  const int rowA = min(row0 + w * 16 + m, N - 1);
  const uint4* Arow = (const uint4*)(Ab + (size_t)rowA * 128);
  uint4 a[4];
#pragma unroll
  for (int kt = 0; kt < 4; kt++) a[kt] = Arow[kt * 4 + quad];
  float4v acc[8];
#pragma unroll
  for (int nt = 0; nt < 8; nt++) acc[nt] = (float4v)0.0f;
#pragma unroll
  for (int nt = 0; nt < 8; nt++) {
#pragma unroll
    for (int kt = 0; kt < 4; kt++) {
      uint4 b = Bl[((kt * 8 + nt) * 4 + quad) * 16 + m];
      acc[nt] = __builtin_amdgcn_mfma_f32_16x16x32_bf16(
          *(short8*)&a[kt], *(short8*)&b, acc[nt], 0, 0, 0);
    }
  }
  unsigned short* Dw = Dl + w * 2048;
  float cm8[8];
#pragma unroll
  for (int nt = 0; nt < 8; nt++) cm8[nt] = 0.f;
#pragma unroll
  for (int r = 0; r < 4; r++) {
    float dv = dvs[w * 16 + quad * 4 + r];
#pragma unroll
    for (int nt = 0; nt < 8; nt++) {
      float fv = acc[nt][r] * dv;
      Dw[(quad * 4 + r) * 128 + nt * 16 + m] = (unsigned short)bf16_rn(fv);
      cm8[nt] = fmaxf(cm8[nt], fabsf(fv));
    }
  }
#pragma unroll
  for (int nt = 0; nt < 8; nt++)
    atomicMax(&cmx[nt * 16 + m], __float_as_uint(cm8[nt]));
  __syncthreads();
  const uint4* Dw4 = (const uint4*)Dw;
#pragma unroll
  for (int p = 0; p < 4; p++) {
    int row = row0 + w * 16 + p * 4 + (lane >> 4);
    if (row < N) {
      ((uint4*)(Lb + (size_t)row * 128))[lane & 15] = Dw4[p * 64 + lane];
    }
  }
  if (t < 128) atomicMax(&colmaxU[t], cmx[t]);
}

// Quantize Lb (bf16, 256B rows) -> L8 (int8 per-column-scale, 128B rows).
__global__ __launch_bounds__(256) void k_quant(
    const unsigned short* __restrict__ Lb, const unsigned* __restrict__ cmU,
    unsigned* __restrict__ L8, int N4) {
  __shared__ float invS[128];
  const int t = threadIdx.x;
  if (t < 128) {
    float cm = __uint_as_float(cmU[t]);
    invS[t] = cm > 0.f ? 127.f / cm : 0.f;
  }
  __syncthreads();
  int idx = blockIdx.x * 256 + t;
  if (idx >= N4) return;
  const int row = idx >> 2;
  const int seg = idx & 3;
  const uint2* src = (const uint2*)(Lb + (size_t)row * 128 + seg * 32);
  const float* inv = invS + seg * 32;
  unsigned d[8];
#pragma unroll
  for (int j = 0; j < 8; j++) {
    float4 f = unpack_bf16x4(src[j]);
    int q0 = __float2int_rn(f.x * inv[j * 4 + 0]);
    int q1 = __float2int_rn(f.y * inv[j * 4 + 1]);
    int q2 = __float2int_rn(f.z * inv[j * 4 + 2]);
    int q3 = __float2int_rn(f.w * inv[j * 4 + 3]);
    q0 = max(-127, min(127, q0));
    q1 = max(-127, min(127, q1));
    q2 = max(-127, min(127, q2));
    q3 = max(-127, min(127, q3));
    d[j] = (unsigned)(q0 & 255) | ((unsigned)(q1 & 255) << 8) |
           ((unsigned)(q2 & 255) << 16) | ((unsigned)(q3 & 255) << 24);
  }
  uint4* dst = (uint4*)((char*)L8 + (size_t)row * 128 + (size_t)seg * 32);
  dst[0] = make_uint4(d[0], d[1], d[2], d[3]);
  dst[1] = make_uint4(d[4], d[5], d[6], d[7]);
}

// gather-accumulate (int8 rows, 128B): integer accumulation, dequant by caller.
__device__ inline int4 gacci(const unsigned* __restrict__ L8d,
                             const int* __restrict__ rows,
                             int st, int dg, int idx, int q32) {
  int4 s0 = make_int4(0, 0, 0, 0), s1 = s0, s2 = s0, s3 = s0;
  for (int b = 0; b < dg; b += 32) {
    int rem = dg - b;
    int mm = rem < 32 ? rem : 32;
    const int cur = idx;
    if (b + 32 < dg) idx = (q32 < rem - 32) ? rows[st + b + 32 + q32] : 0;
    int e = 0;
    for (; e + 8 <= mm; e += 8) {
      int r0 = __shfl(cur, e + 0, 32), r1 = __shfl(cur, e + 1, 32);
      int r2 = __shfl(cur, e + 2, 32), r3 = __shfl(cur, e + 3, 32);
      int r4 = __shfl(cur, e + 4, 32), r5 = __shfl(cur, e + 5, 32);
      int r6 = __shfl(cur, e + 6, 32), r7 = __shfl(cur, e + 7, 32);
      unsigned w0 = L8d[((unsigned)r0 << 5) + q32];
      unsigned w1 = L8d[((unsigned)r1 << 5) + q32];
      unsigned w2 = L8d[((unsigned)r2 << 5) + q32];
      unsigned w3 = L8d[((unsigned)r3 << 5) + q32];
      unsigned w4 = L8d[((unsigned)r4 << 5) + q32];
      unsigned w5 = L8d[((unsigned)r5 << 5) + q32];
      unsigned w6 = L8d[((unsigned)r6 << 5) + q32];
      unsigned w7 = L8d[((unsigned)r7 << 5) + q32];
      accb(s0, w0); accb(s1, w1); accb(s2, w2); accb(s3, w3);
      accb(s0, w4); accb(s1, w5); accb(s2, w6); accb(s3, w7);
    }
    for (; e + 4 <= mm; e += 4) {
      int r0 = __shfl(cur, e + 0, 32), r1 = __shfl(cur, e + 1, 32);
      int r2 = __shfl(cur, e + 2, 32), r3 = __shfl(cur, e + 3, 32);
      unsigned w0 = L8d[((unsigned)r0 << 5) + q32];
      unsigned w1 = L8d[((unsigned)r1 << 5) + q32];
      unsigned w2 = L8d[((unsigned)r2 << 5) + q32];
      unsigned w3 = L8d[((unsigned)r3 << 5) + q32];
      accb(s0, w0); accb(s1, w1); accb(s2, w2); accb(s3, w3);
    }
    for (; e < mm; e++) {
      int r = __shfl(cur, e, 32);
      unsigned w0 = L8d[((unsigned)r << 5) + q32];
      accb(s0, w0);
    }
  }
  int4 acc;
  acc.x = (s0.x + s1.x) + (s2.x + s3.x);
  acc.y = (s0.y + s1.y) + (s2.y + s3.y);
  acc.z = (s0.z + s1.z) + (s2.z + s3.z);
  acc.w = (s0.w + s1.w) + (s2.w + s3.w);
  return acc;
}

// SpMM: self term from bf16 Lb (coalesced), neighbor gather from int8 L8.
// 8 groups x 32 lanes; group owns 2 nodes; both heads hoisted (R8).
// Dequant: accF = self + (float)iacc * (colmax/127), per column.
// MODE 0: a = lrelu(dinv*accF + q*tw + b); write Aout (bf16); BN partials to
// part[block][256] (NO global atomics - R14).
// MODE 1: same a, dot(a,Wout) group-reduced; pacc atomics run-aggregated.
template <int MODE>
__global__ __launch_bounds__(256) void k_spmm(
    const unsigned* __restrict__ Lb, const unsigned* __restrict__ L8d,
    const unsigned* __restrict__ cmU, const int2* __restrict__ meta,
    const int* __restrict__ rows, const float2* __restrict__ dq,
    const float* __restrict__ tw, const float* __restrict__ bias,
    unsigned short* __restrict__ Aout, float* __restrict__ part,
    const float* __restrict__ wout, const int* __restrict__ batch,
    float* __restrict__ pacc, int N) {
  const int t = threadIdx.x;
  const int g = t >> 5;
  const int q32 = t & 31;
  const uint2* __restrict__ L2p = (const uint2*)Lb;
  const float4 t4 = ((const float4*)tw)[q32];
  const float4 b4 = ((const float4*)bias)[q32];
  const float4 cm4 = ((const float4*)(const void*)cmU)[q32];
  const float ksc = 1.f / 127.f;
  const float4 s4 = make_float4(cm4.x * ksc, cm4.y * ksc, cm4.z * ksc, cm4.w * ksc);
  float4 wo4 = make_float4(0.f, 0.f, 0.f, 0.f);
  if (MODE == 1) wo4 = ((const float4*)wout)[q32];
  __shared__ float rs[128], rq[128];
  __shared__ float psum[16];
  __shared__ int pb[16];
  float4 ls = make_float4(0.f, 0.f, 0.f, 0.f), lq = ls;
  if (MODE == 0) {
    if (t < 128) { rs[t] = 0.f; rq[t] = 0.f; }
  } else {
    if (t < 16) pb[t] = -1;
  }
  __syncthreads();
  const int vb = blockIdx.x * 16 + g * 2;
  const bool ok0 = vb < N, ok1 = vb + 1 < N;
  const int v0 = ok0 ? vb : N - 1;
  const int v1 = ok1 ? vb + 1 : N - 1;
  // ---- head: all independent loads for both nodes ----
  const int2 m0 = meta[v0];
  const int2 m1 = meta[v1];
  const float2 dq0 = dq[v0];
  const float2 dq1 = dq[v1];
  uint2 self0 = L2p[((unsigned)v0 << 5) + q32];
  uint2 self1 = L2p[((unsigned)v1 << 5) + q32];
  int bt0 = 0, bt1 = 0;
  if (MODE == 1) { bt0 = batch[v0]; bt1 = batch[v1]; }
  // ---- batch-0 index vectors (depend only on meta) ----
  int i0 = 0, i1 = 0;
  if (q32 < (m0.y < 32 ? m0.y : 32)) i0 = rows[m0.x + q32];
  if (q32 < (m1.y < 32 ? m1.y : 32)) i1 = rows[m1.x + q32];
  // ---- gather both nodes (node 1 has zero head stall) ----
  int4 ia0 = gacci(L8d, rows, m0.x, m0.y, i0, q32);
  int4 ia1 = gacci(L8d, rows, m1.x, m1.y, i1, q32);
  float4 sf0 = unpack_bf16x4(self0);
  float4 sf1 = unpack_bf16x4(self1);
  float4 acc0, acc1;
  acc0.x = sf0.x + (float)ia0.x * s4.x;
  acc0.y = sf0.y + (float)ia0.y * s4.y;
  acc0.z = sf0.z + (float)ia0.z * s4.z;
  acc0.w = sf0.w + (float)ia0.w * s4.w;
  acc1.x = sf1.x + (float)ia1.x * s4.x;
  acc1.y = sf1.y + (float)ia1.y * s4.y;
  acc1.z = sf1.z + (float)ia1.z * s4.z;
  acc1.w = sf1.w + (float)ia1.w * s4.w;
  float4 a0, a1;
  a0.x = LRELU(dq0.x * acc0.x + dq0.y * t4.x + b4.x);
  a0.y = LRELU(dq0.x * acc0.y + dq0.y * t4.y + b4.y);
  a0.z = LRELU(dq0.x * acc0.z + dq0.y * t4.z + b4.z);
  a0.w = LRELU(dq0.x * acc0.w + dq0.y * t4.w + b4.w);
  a1.x = LRELU(dq1.x * acc1.x + dq1.y * t4.x + b4.x);
  a1.y = LRELU(dq1.x * acc1.y + dq1.y * t4.y + b4.y);
  a1.z = LRELU(dq1.x * acc1.z + dq1.y * t4.z + b4.z);
  a1.w = LRELU(dq1.x * acc1.w + dq1.y * t4.w + b4.w);
  if (MODE == 0) {
    if (ok0) {
      uint2 p;
      p.x = pack_bf16x2(a0.x, a0.y);
      p.y = pack_bf16x2(a0.z, a0.w);
      ((uint2*)Aout)[((unsigned)v0 << 5) + q32] = p;
      ls.x += a0.x; ls.y += a0.y; ls.z += a0.z; ls.w += a0.w;
      lq.x += a0.x * a0.x; lq.y += a0.y * a0.y;
      lq.z += a0.z * a0.z; lq.w += a0.w * a0.w;
    }
    if (ok1) {
      uint2 p;
      p.x = pack_bf16x2(a1.x, a1.y);
      p.y = pack_bf16x2(a1.z, a1.w);
      ((uint2*)Aout)[((unsigned)v1 << 5) + q32] = p;
      ls.x += a1.x; ls.y += a1.y; ls.z += a1.z; ls.w += a1.w;
      lq.x += a1.x * a1.x; lq.y += a1.y * a1.y;
      lq.z += a1.z * a1.z; lq.w += a1.w * a1.w;
    }
    const int f0 = q32 * 4;
    atomicAdd(&rs[f0 + 0], ls.x); atomicAdd(&rs[f0 + 1], ls.y);
    atomicAdd(&rs[f0 + 2], ls.z); atomicAdd(&rs[f0 + 3], ls.w);
    atomicAdd(&rq[f0 + 0], lq.x); atomicAdd(&rq[f0 + 1], lq.y);
    atomicAdd(&rq[f0 + 2], lq.z); atomicAdd(&rq[f0 + 3], lq.w);
    __syncthreads();
    if (t < 128) {
      float* pr = part + (size_t)blockIdx.x * 256;
      pr[t] = rs[t];
      pr[128 + t] = rq[t];
    }
  } else {
    float sA = a0.x * wo4.x + a0.y * wo4.y + a0.z * wo4.z + a0.w * wo4.w;
    sA += __shfl_down(sA, 16, 32);
    sA += __shfl_down(sA, 8, 32);
    sA += __shfl_down(sA, 4, 32);
    sA += __shfl_down(sA, 2, 32);
    sA += __shfl_down(sA, 1, 32);
    float sB = a1.x * wo4.x + a1.y * wo4.y + a1.z * wo4.z + a1.w * wo4.w;
    sB += __shfl_down(sB, 16, 32);
    sB += __shfl_down(sB, 8, 32);
    sB += __shfl_down(sB, 4, 32);
    sB += __shfl_down(sB, 2, 32);
    sB += __shfl_down(sB, 1, 32);
    if (q32 == 0) {
      if (ok0) { psum[g * 2 + 0] = sA; pb[g * 2 + 0] = bt0; }
      if (ok1) { psum[g * 2 + 1] = sB; pb[g * 2 + 1] = bt1; }
    }
    __syncthreads();
    if (t < 16) {
      int b = pb[t];
      if (b >= 0 && (t == 0 || pb[t - 1] != b)) {
        float s = psum[t];
        for (int j = t + 1; j < 16 && pb[j] == b; j++) s += psum[j];
        atomicAdd(&pacc[b], s);
      }
    }
  }
}

// Fold BN affine into next layer's weights (parallel: 8 blocks x 16 W-rows).
// Emits bf16 Wb in MFMA B-frag order; tw accumulated atomically (pre-zeroed).
__global__ __launch_bounds__(128) void k_fold(const float* __restrict__ stats,
                                              const float* __restrict__ g,
                                              const float* __restrict__ be,
                                              const float* __restrict__ W,
                                              unsigned short* __restrict__ Wb,
                                              float* __restrict__ tw, float invN) {
  const int j = threadIdx.x;
  const int i0 = blockIdx.x * 16;
  const int nt = j >> 4;
  const int n = j & 15;
  float acc = 0.f;
#pragma unroll
  for (int ii = 0; ii < 16; ii++) {
    int i = i0 + ii;
    float m = stats[i] * invN;
    float var = stats[128 + i] * invN - m * m;
    float si = g[i] * rsqrtf(var + 1e-5f);
    float ti = be[i] - m * si;
    float w = W[i * 128 + j];
    acc += ti * w;
    int kt = i >> 5, quad = (i >> 3) & 3, jj = i & 7;
    Wb[((((kt * 8 + nt) * 4 + quad) * 16 + n) << 3) + jj] =
        (unsigned short)bf16_rn(si * w);
  }
  atomicAdd(&tw[j], acc);
}

__global__ __launch_bounds__(256) void k_out(const float* __restrict__ pacc,
                                             const float* __restrict__ cntG,
                                             const float* __restrict__ bout,
                                             float* __restrict__ out, int G) {
  int i = blockIdx.x * 256 + threadIdx.x;
  if (i < G) out[i] = pacc[i] / fmaxf(cntG[i], 1.0f) + bout[0];
}

extern "C" void kernel_launch(void* const* d_in, const int* in_sizes, int n_in,
                              void* d_out, int out_size, void* d_ws, size_t ws_size,
                              hipStream_t stream) {
  const float* x    = (const float*)d_in[0];
  const int*   ei   = (const int*)d_in[1];
  const int*   batch= (const int*)d_in[2];
  const float* W0   = (const float*)d_in[3];
  const float* b0   = (const float*)d_in[4];
  const float* W1   = (const float*)d_in[5];
  const float* b1   = (const float*)d_in[6];
  const float* W2   = (const float*)d_in[7];
  const float* b2   = (const float*)d_in[8];
  const float* W3   = (const float*)d_in[9];
  const float* b3   = (const float*)d_in[10];
  const float* g1   = (const float*)d_in[11];
  const float* be1  = (const float*)d_in[12];
  const float* g2   = (const float*)d_in[13];
  const float* be2  = (const float*)d_in[14];
  const float* g3   = (const float*)d_in[15];
  const float* be3  = (const float*)d_in[16];
  const float* Wout = (const float*)d_in[17];
  const float* bout = (const float*)d_in[18];
  float* out = (float*)d_out;

  const int N = in_sizes[0] / 9;
  const int E = in_sizes[1] / 2;
  const int G = out_size;

  char* w = (char*)d_ws;
  auto alloc = [&](size_t bytes) -> void* {
    void* p = (void*)w;
    w += (bytes + 255) & ~(size_t)255;
    return p;
  };
  // ---- zeroed region (ONE memset) ----
  char* zbase = w;
  int*   cnt    = (int*)alloc((size_t)N * 4);
  float* pacc   = (float*)alloc((size_t)G * 4);
  float* stats  = (float*)alloc(3 * 256 * 4);
  float* tw3    = (float*)alloc(3 * 128 * 4);
  unsigned* cmU3 = (unsigned*)alloc(3 * 128 * 4);  // per-layer col absmax (bits)
  size_t zsize = (size_t)(w - zbase);
  // ---- non-zeroed ----
  int*   offs   = (int*)alloc((size_t)N * 4);
  int*   incl   = (int*)alloc((size_t)N * 4);
  int*   bsums  = (int*)alloc(512 * 4);
  int*   bpref  = (int*)alloc(512 * 4);
  float* dinv   = (float*)alloc((size_t)N * 4);
  float2* dq    = (float2*)alloc((size_t)N * 8);
  int2*  meta   = (int2*)alloc((size_t)N * 8);
  float* cntG   = (float*)alloc((size_t)G * 4);
  int*   rank   = (int*)alloc((size_t)E * 4);
  int*   rows   = (int*)alloc((size_t)E * 4);
  unsigned short* Wb = (unsigned short*)alloc(128 * 128 * 2);  // bf16 B-frag layout
  unsigned* u   = (unsigned*)alloc((size_t)N * 12 * 2);        // bf16, 24B rows
  float* ax     = (float*)alloc((size_t)N * 12 * 4);
  unsigned* Lb  = (unsigned*)alloc((size_t)N * 128 * 2);       // bf16 rows, 256B
  unsigned* L8  = (unsigned*)alloc((size_t)N * 128);           // int8 rows, 128B
  unsigned short* Abuf = (unsigned short*)alloc((size_t)N * 128 * 2);  // bf16 acts
  const int sb  = (N + 15) / 16;    // spmm / spmm9 / gemm_in blocks
  float* part   = (float*)alloc((size_t)sb * 256 * 4);  // per-block BN partials

  hipMemsetAsync(zbase, 0, zsize, stream);

  const int eb  = (E + 255) / 256;
  const int nbN = (N + 255) / 256;  // also the scan block count (must be <= 512)
  const int mb  = (N + 63) / 64;    // mfma gemm blocks
  const int qb  = (N * 4 + 255) / 256;  // quant blocks
  const float invN = 1.0f / (float)N;
  float* twA = tw3;
  float* twB = tw3 + 128;
  float* twC = tw3 + 256;
  unsigned* cmA = cmU3;
  unsigned* cmB = cmU3 + 128;
  unsigned* cmC = cmU3 + 256;

  // --- graph preprocessing ---
  k_count<<<eb, 256, 0, stream>>>(ei, cnt, rank, E);
  k_scan1<<<nbN, 256, 0, stream>>>(cnt, incl, bsums, dinv, N);
  k_scan2<<<1, 512, 0, stream>>>(bsums, bpref, nbN);
  k_scan3_prep<<<nbN, 256, 0, stream>>>(incl, cnt, bpref, offs, meta, x, dinv, u, N);
  k_csr<<<eb, 256, 0, stream>>>(ei, offs, rank, rows, E);
  k_cntg<<<(G + 255) / 256, 256, 0, stream>>>(batch, cntG, N, G);

  // --- layer 1: aggregate 9-dim input first (A x) @ W0; also emits dq ---
  k_spmm9<<<sb, 256, 0, stream>>>((const unsigned short*)u, meta, rows,
                                  dinv, ax, dq, N);
  k_gemm_in<<<sb, 256, 0, stream>>>(ax, W0, b0, Abuf, part, N);
  k_redstats<<<64, 256, 0, stream>>>(part, stats, sb);
  // --- layer 2 ---
  k_fold<<<8, 128, 0, stream>>>(stats, g1, be1, W1, Wb, twA, invN);
  k_gemm_mfma<<<mb, 256, 0, stream>>>(Abuf, (const uint4*)Wb, dinv,
                                      (unsigned short*)Lb, cmA, N);
  k_quant<<<qb, 256, 0, stream>>>((const unsigned short*)Lb, cmA, L8, N * 4);
  k_spmm<0><<<sb, 256, 0, stream>>>(Lb, L8, cmA, meta, rows, dq, twA, b1,
                                    Abuf, part, nullptr, nullptr, nullptr, N);
  k_redstats<<<64, 256, 0, stream>>>(part, stats + 256, sb);
  // --- layer 3 ---
  k_fold<<<8, 128, 0, stream>>>(stats + 256, g2, be2, W2, Wb, twB, invN);
  k_gemm_mfma<<<mb, 256, 0, stream>>>(Abuf, (const uint4*)Wb, dinv,
                                      (unsigned short*)Lb, cmB, N);
  k_quant<<<qb, 256, 0, stream>>>((const unsigned short*)Lb, cmB, L8, N * 4);
  k_spmm<0><<<sb, 256, 0, stream>>>(Lb, L8, cmB, meta, rows, dq, twB, b2,
                                    Abuf, part, nullptr, nullptr, nullptr, N);
  k_redstats<<<64, 256, 0, stream>>>(part, stats + 512, sb);
  // --- layer 4 (+ fused pool @ Wout) ---
  k_fold<<<8, 128, 0, stream>>>(stats + 512, g3, be3, W3, Wb, twC, invN);
  k_gemm_mfma<<<mb, 256, 0, stream>>>(Abuf, (const uint4*)Wb, dinv,
                                      (unsigned short*)Lb, cmC, N);
  k_quant<<<qb, 256, 0, stream>>>((const unsigned short*)Lb, cmC, L8, N * 4);
  k_spmm<1><<<sb, 256, 0, stream>>>(Lb, L8, cmC, meta, rows, dq, twC, b3,
                                    nullptr, nullptr, Wout, batch, pacc, N);
  k_out<<<(G + 255) / 256, 256, 0, stream>>>(pacc, cntG, bout, out, G);
}

// Round 8
// 682.842 us; speedup vs baseline: 1.5290x; 1.0611x over previous
//
#include <hip/hip_runtime.h>

// GCN forward: 4x [GEMM -> symmetric-normalized aggregation -> lrelu -> BN(folded)]
// then mean-pool per graph @ Wout.
//
// Key structure:
//  - CSR via counting sort, rank captured in count pass -> placement pass NO atomics.
//  - Layer 1 commuted: A(x@W0) = (Ax)@W0; u bf16 32B-padded rows (R15; 3.2MB
//    L2-resident, 1 line/edge aligned).
//  - dinv folded into GEMM/gather epilogues; BN folded into next GEMM.
//  - R9 fp8 failed accuracy; R10/R11 int8 col-scale gather (order-free int accum).
//  - R14 CONFIRMED: stats atomic storm (6250 blocks x 256 atomicAdds into 1KB)
//    was serializing k_gemm_in (164us) AND masking k_spmm (180->100us when
//    replaced by per-block partials + k_redstats).
//  - k_spmm floor model (R4/R12/R13/R14): time = lines x latency / ~20 MSHR
//    in-flight lines per CU. 2 lines/edge (128B int8 row) x ~385cy mixed
//    L2/L3 latency -> ~100us/dispatch = structural floor. 1 line/edge needs
//    int4/int6 (accuracy-dead); residency plays capped by reuse/line/XCD~2.
//  - R15: u padded 24->32B (spmm9 lines 1.25->1.0), gemm_in float4 loads,
//    k_cntg fused into k_out, redstats 128 blocks.
//  - Final layer fuses pool; pacc atomics run-aggregated per block.

#define LRELU(z) ((z) > 0.f ? (z) : 0.01f * (z))

typedef __attribute__((ext_vector_type(8))) short short8;
typedef __attribute__((ext_vector_type(4))) float float4v;

__device__ inline unsigned bf16_rn(float a) {
  unsigned u = __float_as_uint(a);
  return (u + 0x7FFFu + ((u >> 16) & 1u)) >> 16;
}

__device__ inline unsigned pack_bf16x2(float a, float b) {
  return bf16_rn(a) | (bf16_rn(b) << 16);
}

__device__ inline float bf16f(unsigned short s) {
  return __uint_as_float(((unsigned)s) << 16);
}

__device__ inline float4 unpack_bf16x4(uint2 u) {
  float4 r;
  r.x = __uint_as_float(u.x << 16);
  r.y = __uint_as_float(u.x & 0xffff0000u);
  r.z = __uint_as_float(u.y << 16);
  r.w = __uint_as_float(u.y & 0xffff0000u);
  return r;
}

// sign-extend 4 packed int8 lanes of v into int4 accumulator d
__device__ inline void accb(int4& d, unsigned v) {
  d.x += ((int)(v << 24)) >> 24;
  d.y += ((int)(v << 16)) >> 24;
  d.z += ((int)(v << 8)) >> 24;
  d.w += ((int)v) >> 24;
}

// count pass: cnt[col]++ and record each edge's rank within its column.
__global__ __launch_bounds__(256) void k_count(const int* __restrict__ ei,
                                               int* __restrict__ cnt,
                                               int* __restrict__ rank, int E) {
  int i = blockIdx.x * 256 + threadIdx.x;
  if (i < E) rank[i] = atomicAdd(&cnt[ei[E + i]], 1);
}

// block-scan of cnt + dinv fused
__global__ __launch_bounds__(256) void k_scan1(const int* __restrict__ cnt,
                                               int* __restrict__ incl,
                                               int* __restrict__ bsums,
                                               float* __restrict__ dinv, int N) {
  __shared__ int s[256];
  int tid = threadIdx.x;
  int idx = blockIdx.x * 256 + tid;
  int v = (idx < N) ? cnt[idx] : 0;
  if (idx < N) dinv[idx] = rsqrtf((float)(v + 1));
  s[tid] = v;
  __syncthreads();
  for (int off = 1; off < 256; off <<= 1) {
    int t = (tid >= off) ? s[tid - off] : 0;
    __syncthreads();
    s[tid] += t;
    __syncthreads();
  }
  if (idx < N) incl[idx] = s[tid];
  if (tid == 255) bsums[blockIdx.x] = s[255];
}

// nb must be <= 512 (N <= 131072 here: nb = 391)
__global__ __launch_bounds__(512) void k_scan2(const int* __restrict__ bsums,
                                               int* __restrict__ bpref, int nb) {
  __shared__ int s[512];
  int tid = threadIdx.x;
  int v = (tid < nb) ? bsums[tid] : 0;
  s[tid] = v;
  __syncthreads();
  for (int off = 1; off < 512; off <<= 1) {
    int t = (tid >= off) ? s[tid - off] : 0;
    __syncthreads();
    s[tid] += t;
    __syncthreads();
  }
  bpref[tid] = s[tid] - v;  // exclusive prefix of block sums
}

// offs computation + u preparation fused: u[v][0:9] = bf16(x[v][0:9]*dinv[v]),
// slot 9 = bf16(dinv[v]), slots 10..15 = 0. 32B-padded rows (R15: 1 aligned
// line per gather). Also emits meta=(offs,cnt).
__global__ __launch_bounds__(256) void k_scan3_prep(
    const int* __restrict__ incl, const int* __restrict__ cnt,
    const int* __restrict__ bpref, int* __restrict__ offs,
    int2* __restrict__ meta, const float* __restrict__ x,
    const float* __restrict__ dinv, unsigned* __restrict__ u, int N) {
  int idx = blockIdx.x * 256 + threadIdx.x;
  if (idx >= N) return;
  int c = cnt[idx];
  int off = incl[idx] - c + bpref[blockIdx.x];
  offs[idx] = off;
  meta[idx] = make_int2(off, c);
  float dv = dinv[idx];
  const float* xr = x + (size_t)idx * 9;
  unsigned p0 = pack_bf16x2(xr[0] * dv, xr[1] * dv);
  unsigned p1 = pack_bf16x2(xr[2] * dv, xr[3] * dv);
  unsigned p2 = pack_bf16x2(xr[4] * dv, xr[5] * dv);
  unsigned p3 = pack_bf16x2(xr[6] * dv, xr[7] * dv);
  unsigned p4 = pack_bf16x2(xr[8] * dv, dv);
  uint4* u4 = (uint4*)u;
  u4[(size_t)idx * 2 + 0] = make_uint4(p0, p1, p2, p3);
  u4[(size_t)idx * 2 + 1] = make_uint4(p4, 0u, 0u, 0u);
}

// CSR placement: NO atomics (offs random read + rank from count pass).
__global__ __launch_bounds__(256) void k_csr(const int* __restrict__ ei,
                                             const int* __restrict__ offs,
                                             const int* __restrict__ rank,
                                             int* __restrict__ rows, int E) {
  int i = blockIdx.x * 256 + threadIdx.x;
  if (i < E) {
    int c = ei[E + i];
    rows[offs[c] + rank[i]] = ei[i];
  }
}

// ax[v] = dinv[v]*(u[v] + sum_in u[row]); lane 9 accumulates sum_in dinv[row]
// and emits dq[v] = (dinv, dinv*(dinv+sd)). 16-lane group per node.
// u rows are 16 ushorts (32B, padded).
__global__ __launch_bounds__(256) void k_spmm9(
    const unsigned short* __restrict__ u, const int2* __restrict__ meta,
    const int* __restrict__ rows, const float* __restrict__ dinv,
    float* __restrict__ ax, float2* __restrict__ dq, int N) {
  const int t = threadIdx.x;
  const int g = t >> 4;
  const int f = t & 15;
  const int v = blockIdx.x * 16 + g;
  if (v >= N) return;
  const int2 m = meta[v];
  const int st = m.x;
  const int dg = m.y;
  const float dv = dinv[v];
  const bool act = (f < 10);
  float a0 = (f < 9) ? bf16f(u[(unsigned)v * 16u + f]) : 0.f;
  float a1 = 0.f, a2 = 0.f, a3 = 0.f;
  int idx = 0;
  if (f < (dg < 16 ? dg : 16)) idx = rows[st + f];
  for (int b = 0; b < dg; b += 16) {
    int rem = dg - b;
    int mm = rem < 16 ? rem : 16;
    const int cur = idx;
    if (b + 16 < dg) idx = (f < rem - 16) ? rows[st + b + 16 + f] : 0;
    int e = 0;
    for (; e + 8 <= mm; e += 8) {
      int r0 = __shfl(cur, e + 0, 16), r1 = __shfl(cur, e + 1, 16);
      int r2 = __shfl(cur, e + 2, 16), r3 = __shfl(cur, e + 3, 16);
      int r4 = __shfl(cur, e + 4, 16), r5 = __shfl(cur, e + 5, 16);
      int r6 = __shfl(cur, e + 6, 16), r7 = __shfl(cur, e + 7, 16);
      float x0 = 0, x1 = 0, x2 = 0, x3 = 0, x4 = 0, x5 = 0, x6 = 0, x7 = 0;
      if (act) {
        x0 = bf16f(u[(unsigned)r0 * 16u + f]); x1 = bf16f(u[(unsigned)r1 * 16u + f]);
        x2 = bf16f(u[(unsigned)r2 * 16u + f]); x3 = bf16f(u[(unsigned)r3 * 16u + f]);
        x4 = bf16f(u[(unsigned)r4 * 16u + f]); x5 = bf16f(u[(unsigned)r5 * 16u + f]);
        x6 = bf16f(u[(unsigned)r6 * 16u + f]); x7 = bf16f(u[(unsigned)r7 * 16u + f]);
      }
      a0 += x0; a1 += x1; a2 += x2; a3 += x3;
      a0 += x4; a1 += x5; a2 += x6; a3 += x7;
    }
    for (; e + 4 <= mm; e += 4) {
      int r0 = __shfl(cur, e + 0, 16), r1 = __shfl(cur, e + 1, 16);
      int r2 = __shfl(cur, e + 2, 16), r3 = __shfl(cur, e + 3, 16);
      float x0 = 0, x1 = 0, x2 = 0, x3 = 0;
      if (act) {
        x0 = bf16f(u[(unsigned)r0 * 16u + f]); x1 = bf16f(u[(unsigned)r1 * 16u + f]);
        x2 = bf16f(u[(unsigned)r2 * 16u + f]); x3 = bf16f(u[(unsigned)r3 * 16u + f]);
      }
      a0 += x0; a1 += x1; a2 += x2; a3 += x3;
    }
    for (; e < mm; e++) {
      int r = __shfl(cur, e, 16);
      if (act) a0 += bf16f(u[(unsigned)r * 16u + f]);
    }
  }
  float sum = (a0 + a1) + (a2 + a3);
  if (f < 9) {
    ax[(unsigned)v * 12u + f] = sum * dv;
  } else if (f == 9) {
    dq[v] = make_float2(dv, dv * (dv + sum));
  }
}

// h1 = lrelu(ax[v][0:9] @ W0 + b0); writes Abuf (bf16); per-block BN partials
// to part[block][256] (NO global atomics - R14). float4 ax loads (R15).
__global__ __launch_bounds__(256) void k_gemm_in(
    const float* __restrict__ ax, const float* __restrict__ W0,
    const float* __restrict__ b0, unsigned short* __restrict__ Abuf,
    float* __restrict__ part, int N) {
  __shared__ float Wl[9 * 128];
  __shared__ float rs[128], rq[128];
  const int t = threadIdx.x;
  for (int i = t; i < 9 * 128; i += 256) Wl[i] = W0[i];
  if (t < 128) { rs[t] = 0.f; rq[t] = 0.f; }
  __syncthreads();
  const int col = t & 127;
  const int rsub = t >> 7;
  const int base = blockIdx.x * 16;
  const float bc = b0[col];
  float ls = 0.f, lq = 0.f;
  for (int it = 0; it < 8; it++) {
    int row = base + it * 2 + rsub;
    if (row < N) {
      const float4* ar4 = (const float4*)(ax + (size_t)row * 12);
      float4 v0 = ar4[0], v1 = ar4[1], v2 = ar4[2];
      float acc = bc;
      acc += v0.x * Wl[0 * 128 + col];
      acc += v0.y * Wl[1 * 128 + col];
      acc += v0.z * Wl[2 * 128 + col];
      acc += v0.w * Wl[3 * 128 + col];
      acc += v1.x * Wl[4 * 128 + col];
      acc += v1.y * Wl[5 * 128 + col];
      acc += v1.z * Wl[6 * 128 + col];
      acc += v1.w * Wl[7 * 128 + col];
      acc += v2.x * Wl[8 * 128 + col];
      float a = LRELU(acc);
      Abuf[(size_t)row * 128 + col] = (unsigned short)bf16_rn(a);
      ls += a;
      lq += a * a;
    }
  }
  atomicAdd(&rs[col], ls);
  atomicAdd(&rq[col], lq);
  __syncthreads();
  if (t < 128) {
    float* pr = part + (size_t)blockIdx.x * 256;
    pr[t] = rs[t];
    pr[128 + t] = rq[t];
  }
}

// Reduce per-block partials part[nrows][256] into stats[256] (few atomics).
__global__ __launch_bounds__(256) void k_redstats(const float* __restrict__ part,
                                                  float* __restrict__ stats,
                                                  int nrows) {
  const int t = threadIdx.x;
  float s = 0.f;
  for (int r = blockIdx.x; r < nrows; r += gridDim.x)
    s += part[(size_t)r * 256 + t];
  atomicAdd(&stats[t], s);
}

// bf16 MFMA GEMM: L[v][:] = bf16((A[v][:] @ Wf) * dinv[v]).
// Block: 64 rows, 4 waves x (16 rows x 128 cols). Wb pre-swizzled B-frag order.
// Also reduces per-column absmax of L into colmaxU.
__global__ __launch_bounds__(256) void k_gemm_mfma(
    const unsigned short* __restrict__ Ab, const uint4* __restrict__ Wb,
    const float* __restrict__ dinv, unsigned short* __restrict__ Lb,
    unsigned* __restrict__ colmaxU, int N) {
  __shared__ uint4 Bl[2048];               // 32 KB: all B fragments
  __shared__ unsigned short Dl[4 * 2048];  // 16 KB: per-wave D staging
  __shared__ float dvs[64];
  __shared__ unsigned cmx[128];
  const int t = threadIdx.x;
  const int row0 = blockIdx.x * 64;
#pragma unroll
  for (int i = 0; i < 8; i++) Bl[t + i * 256] = Wb[t + i * 256];
  if (t < 128) cmx[t] = 0u;
  if (t < 64) {
    int r = row0 + t;
    dvs[t] = (r < N) ? dinv[r] : 0.f;
  }
  __syncthreads();
  const int w = t >> 6;
  const int lane = t & 63;
  const int m = lane & 15;
  const int quad = lane >> 4;
  const int rowA = min(row0 + w * 16 + m, N - 1);
  const uint4* Arow = (const uint4*)(Ab + (size_t)rowA * 128);
  uint4 a[4];
#pragma unroll
  for (int kt = 0; kt < 4; kt++) a[kt] = Arow[kt * 4 + quad];
  float4v acc[8];
#pragma unroll
  for (int nt = 0; nt < 8; nt++) acc[nt] = (float4v)0.0f;
#pragma unroll
  for (int nt = 0; nt < 8; nt++) {
#pragma unroll
    for (int kt = 0; kt < 4; kt++) {
      uint4 b = Bl[((kt * 8 + nt) * 4 + quad) * 16 + m];
      acc[nt] = __builtin_amdgcn_mfma_f32_16x16x32_bf16(
          *(short8*)&a[kt], *(short8*)&b, acc[nt], 0, 0, 0);
    }
  }
  unsigned short* Dw = Dl + w * 2048;
  float cm8[8];
#pragma unroll
  for (int nt = 0; nt < 8; nt++) cm8[nt] = 0.f;
#pragma unroll
  for (int r = 0; r < 4; r++) {
    float dv = dvs[w * 16 + quad * 4 + r];
#pragma unroll
    for (int nt = 0; nt < 8; nt++) {
      float fv = acc[nt][r] * dv;
      Dw[(quad * 4 + r) * 128 + nt * 16 + m] = (unsigned short)bf16_rn(fv);
      cm8[nt] = fmaxf(cm8[nt], fabsf(fv));
    }
  }
#pragma unroll
  for (int nt = 0; nt < 8; nt++)
    atomicMax(&cmx[nt * 16 + m], __float_as_uint(cm8[nt]));
  __syncthreads();
  const uint4* Dw4 = (const uint4*)Dw;
#pragma unroll
  for (int p = 0; p < 4; p++) {
    int row = row0 + w * 16 + p * 4 + (lane >> 4);
    if (row < N) {
      ((uint4*)(Lb + (size_t)row * 128))[lane & 15] = Dw4[p * 64 + lane];
    }
  }
  if (t < 128) atomicMax(&colmaxU[t], cmx[t]);
}

// Quantize Lb (bf16, 256B rows) -> L8 (int8 per-column-scale, 128B rows).
__global__ __launch_bounds__(256) void k_quant(
    const unsigned short* __restrict__ Lb, const unsigned* __restrict__ cmU,
    unsigned* __restrict__ L8, int N4) {
  __shared__ float invS[128];
  const int t = threadIdx.x;
  if (t < 128) {
    float cm = __uint_as_float(cmU[t]);
    invS[t] = cm > 0.f ? 127.f / cm : 0.f;
  }
  __syncthreads();
  int idx = blockIdx.x * 256 + t;
  if (idx >= N4) return;
  const int row = idx >> 2;
  const int seg = idx & 3;
  const uint2* src = (const uint2*)(Lb + (size_t)row * 128 + seg * 32);
  const float* inv = invS + seg * 32;
  unsigned d[8];
#pragma unroll
  for (int j = 0; j < 8; j++) {
    float4 f = unpack_bf16x4(src[j]);
    int q0 = __float2int_rn(f.x * inv[j * 4 + 0]);
    int q1 = __float2int_rn(f.y * inv[j * 4 + 1]);
    int q2 = __float2int_rn(f.z * inv[j * 4 + 2]);
    int q3 = __float2int_rn(f.w * inv[j * 4 + 3]);
    q0 = max(-127, min(127, q0));
    q1 = max(-127, min(127, q1));
    q2 = max(-127, min(127, q2));
    q3 = max(-127, min(127, q3));
    d[j] = (unsigned)(q0 & 255) | ((unsigned)(q1 & 255) << 8) |
           ((unsigned)(q2 & 255) << 16) | ((unsigned)(q3 & 255) << 24);
  }
  uint4* dst = (uint4*)((char*)L8 + (size_t)row * 128 + (size_t)seg * 32);
  dst[0] = make_uint4(d[0], d[1], d[2], d[3]);
  dst[1] = make_uint4(d[4], d[5], d[6], d[7]);
}

// gather-accumulate (int8 rows, 128B): integer accumulation, dequant by caller.
__device__ inline int4 gacci(const unsigned* __restrict__ L8d,
                             const int* __restrict__ rows,
                             int st, int dg, int idx, int q32) {
  int4 s0 = make_int4(0, 0, 0, 0), s1 = s0, s2 = s0, s3 = s0;
  for (int b = 0; b < dg; b += 32) {
    int rem = dg - b;
    int mm = rem < 32 ? rem : 32;
    const int cur = idx;
    if (b + 32 < dg) idx = (q32 < rem - 32) ? rows[st + b + 32 + q32] : 0;
    int e = 0;
    for (; e + 8 <= mm; e += 8) {
      int r0 = __shfl(cur, e + 0, 32), r1 = __shfl(cur, e + 1, 32);
      int r2 = __shfl(cur, e + 2, 32), r3 = __shfl(cur, e + 3, 32);
      int r4 = __shfl(cur, e + 4, 32), r5 = __shfl(cur, e + 5, 32);
      int r6 = __shfl(cur, e + 6, 32), r7 = __shfl(cur, e + 7, 32);
      unsigned w0 = L8d[((unsigned)r0 << 5) + q32];
      unsigned w1 = L8d[((unsigned)r1 << 5) + q32];
      unsigned w2 = L8d[((unsigned)r2 << 5) + q32];
      unsigned w3 = L8d[((unsigned)r3 << 5) + q32];
      unsigned w4 = L8d[((unsigned)r4 << 5) + q32];
      unsigned w5 = L8d[((unsigned)r5 << 5) + q32];
      unsigned w6 = L8d[((unsigned)r6 << 5) + q32];
      unsigned w7 = L8d[((unsigned)r7 << 5) + q32];
      accb(s0, w0); accb(s1, w1); accb(s2, w2); accb(s3, w3);
      accb(s0, w4); accb(s1, w5); accb(s2, w6); accb(s3, w7);
    }
    for (; e + 4 <= mm; e += 4) {
      int r0 = __shfl(cur, e + 0, 32), r1 = __shfl(cur, e + 1, 32);
      int r2 = __shfl(cur, e + 2, 32), r3 = __shfl(cur, e + 3, 32);
      unsigned w0 = L8d[((unsigned)r0 << 5) + q32];
      unsigned w1 = L8d[((unsigned)r1 << 5) + q32];
      unsigned w2 = L8d[((unsigned)r2 << 5) + q32];
      unsigned w3 = L8d[((unsigned)r3 << 5) + q32];
      accb(s0, w0); accb(s1, w1); accb(s2, w2); accb(s3, w3);
    }
    for (; e < mm; e++) {
      int r = __shfl(cur, e, 32);
      unsigned w0 = L8d[((unsigned)r << 5) + q32];
      accb(s0, w0);
    }
  }
  int4 acc;
  acc.x = (s0.x + s1.x) + (s2.x + s3.x);
  acc.y = (s0.y + s1.y) + (s2.y + s3.y);
  acc.z = (s0.z + s1.z) + (s2.z + s3.z);
  acc.w = (s0.w + s1.w) + (s2.w + s3.w);
  return acc;
}

// SpMM: self term from bf16 Lb (coalesced), neighbor gather from int8 L8.
// 8 groups x 32 lanes; group owns 2 nodes; both heads hoisted (R8).
// Dequant: accF = self + (float)iacc * (colmax/127), per column.
// MODE 0: a = lrelu(dinv*accF + q*tw + b); write Aout (bf16); BN partials to
// part[block][256] (NO global atomics - R14).
// MODE 1: same a, dot(a,Wout) group-reduced; pacc atomics run-aggregated.
template <int MODE>
__global__ __launch_bounds__(256) void k_spmm(
    const unsigned* __restrict__ Lb, const unsigned* __restrict__ L8d,
    const unsigned* __restrict__ cmU, const int2* __restrict__ meta,
    const int* __restrict__ rows, const float2* __restrict__ dq,
    const float* __restrict__ tw, const float* __restrict__ bias,
    unsigned short* __restrict__ Aout, float* __restrict__ part,
    const float* __restrict__ wout, const int* __restrict__ batch,
    float* __restrict__ pacc, int N) {
  const int t = threadIdx.x;
  const int g = t >> 5;
  const int q32 = t & 31;
  const uint2* __restrict__ L2p = (const uint2*)Lb;
  const float4 t4 = ((const float4*)tw)[q32];
  const float4 b4 = ((const float4*)bias)[q32];
  const float4 cm4 = ((const float4*)(const void*)cmU)[q32];
  const float ksc = 1.f / 127.f;
  const float4 s4 = make_float4(cm4.x * ksc, cm4.y * ksc, cm4.z * ksc, cm4.w * ksc);
  float4 wo4 = make_float4(0.f, 0.f, 0.f, 0.f);
  if (MODE == 1) wo4 = ((const float4*)wout)[q32];
  __shared__ float rs[128], rq[128];
  __shared__ float psum[16];
  __shared__ int pb[16];
  float4 ls = make_float4(0.f, 0.f, 0.f, 0.f), lq = ls;
  if (MODE == 0) {
    if (t < 128) { rs[t] = 0.f; rq[t] = 0.f; }
  } else {
    if (t < 16) pb[t] = -1;
  }
  __syncthreads();
  const int vb = blockIdx.x * 16 + g * 2;
  const bool ok0 = vb < N, ok1 = vb + 1 < N;
  const int v0 = ok0 ? vb : N - 1;
  const int v1 = ok1 ? vb + 1 : N - 1;
  // ---- head: all independent loads for both nodes ----
  const int2 m0 = meta[v0];
  const int2 m1 = meta[v1];
  const float2 dq0 = dq[v0];
  const float2 dq1 = dq[v1];
  uint2 self0 = L2p[((unsigned)v0 << 5) + q32];
  uint2 self1 = L2p[((unsigned)v1 << 5) + q32];
  int bt0 = 0, bt1 = 0;
  if (MODE == 1) { bt0 = batch[v0]; bt1 = batch[v1]; }
  // ---- batch-0 index vectors (depend only on meta) ----
  int i0 = 0, i1 = 0;
  if (q32 < (m0.y < 32 ? m0.y : 32)) i0 = rows[m0.x + q32];
  if (q32 < (m1.y < 32 ? m1.y : 32)) i1 = rows[m1.x + q32];
  // ---- gather both nodes (node 1 has zero head stall) ----
  int4 ia0 = gacci(L8d, rows, m0.x, m0.y, i0, q32);
  int4 ia1 = gacci(L8d, rows, m1.x, m1.y, i1, q32);
  float4 sf0 = unpack_bf16x4(self0);
  float4 sf1 = unpack_bf16x4(self1);
  float4 acc0, acc1;
  acc0.x = sf0.x + (float)ia0.x * s4.x;
  acc0.y = sf0.y + (float)ia0.y * s4.y;
  acc0.z = sf0.z + (float)ia0.z * s4.z;
  acc0.w = sf0.w + (float)ia0.w * s4.w;
  acc1.x = sf1.x + (float)ia1.x * s4.x;
  acc1.y = sf1.y + (float)ia1.y * s4.y;
  acc1.z = sf1.z + (float)ia1.z * s4.z;
  acc1.w = sf1.w + (float)ia1.w * s4.w;
  float4 a0, a1;
  a0.x = LRELU(dq0.x * acc0.x + dq0.y * t4.x + b4.x);
  a0.y = LRELU(dq0.x * acc0.y + dq0.y * t4.y + b4.y);
  a0.z = LRELU(dq0.x * acc0.z + dq0.y * t4.z + b4.z);
  a0.w = LRELU(dq0.x * acc0.w + dq0.y * t4.w + b4.w);
  a1.x = LRELU(dq1.x * acc1.x + dq1.y * t4.x + b4.x);
  a1.y = LRELU(dq1.x * acc1.y + dq1.y * t4.y + b4.y);
  a1.z = LRELU(dq1.x * acc1.z + dq1.y * t4.z + b4.z);
  a1.w = LRELU(dq1.x * acc1.w + dq1.y * t4.w + b4.w);
  if (MODE == 0) {
    if (ok0) {
      uint2 p;
      p.x = pack_bf16x2(a0.x, a0.y);
      p.y = pack_bf16x2(a0.z, a0.w);
      ((uint2*)Aout)[((unsigned)v0 << 5) + q32] = p;
      ls.x += a0.x; ls.y += a0.y; ls.z += a0.z; ls.w += a0.w;
      lq.x += a0.x * a0.x; lq.y += a0.y * a0.y;
      lq.z += a0.z * a0.z; lq.w += a0.w * a0.w;
    }
    if (ok1) {
      uint2 p;
      p.x = pack_bf16x2(a1.x, a1.y);
      p.y = pack_bf16x2(a1.z, a1.w);
      ((uint2*)Aout)[((unsigned)v1 << 5) + q32] = p;
      ls.x += a1.x; ls.y += a1.y; ls.z += a1.z; ls.w += a1.w;
      lq.x += a1.x * a1.x; lq.y += a1.y * a1.y;
      lq.z += a1.z * a1.z; lq.w += a1.w * a1.w;
    }
    const int f0 = q32 * 4;
    atomicAdd(&rs[f0 + 0], ls.x); atomicAdd(&rs[f0 + 1], ls.y);
    atomicAdd(&rs[f0 + 2], ls.z); atomicAdd(&rs[f0 + 3], ls.w);
    atomicAdd(&rq[f0 + 0], lq.x); atomicAdd(&rq[f0 + 1], lq.y);
    atomicAdd(&rq[f0 + 2], lq.z); atomicAdd(&rq[f0 + 3], lq.w);
    __syncthreads();
    if (t < 128) {
      float* pr = part + (size_t)blockIdx.x * 256;
      pr[t] = rs[t];
      pr[128 + t] = rq[t];
    }
  } else {
    float sA = a0.x * wo4.x + a0.y * wo4.y + a0.z * wo4.z + a0.w * wo4.w;
    sA += __shfl_down(sA, 16, 32);
    sA += __shfl_down(sA, 8, 32);
    sA += __shfl_down(sA, 4, 32);
    sA += __shfl_down(sA, 2, 32);
    sA += __shfl_down(sA, 1, 32);
    float sB = a1.x * wo4.x + a1.y * wo4.y + a1.z * wo4.z + a1.w * wo4.w;
    sB += __shfl_down(sB, 16, 32);
    sB += __shfl_down(sB, 8, 32);
    sB += __shfl_down(sB, 4, 32);
    sB += __shfl_down(sB, 2, 32);
    sB += __shfl_down(sB, 1, 32);
    if (q32 == 0) {
      if (ok0) { psum[g * 2 + 0] = sA; pb[g * 2 + 0] = bt0; }
      if (ok1) { psum[g * 2 + 1] = sB; pb[g * 2 + 1] = bt1; }
    }
    __syncthreads();
    if (t < 16) {
      int b = pb[t];
      if (b >= 0 && (t == 0 || pb[t - 1] != b)) {
        float s = psum[t];
        for (int j = t + 1; j < 16 && pb[j] == b; j++) s += psum[j];
        atomicAdd(&pacc[b], s);
      }
    }
  }
}

// Fold BN affine into next layer's weights (parallel: 8 blocks x 16 W-rows).
// Emits bf16 Wb in MFMA B-frag order; tw accumulated atomically (pre-zeroed).
__global__ __launch_bounds__(128) void k_fold(const float* __restrict__ stats,
                                              const float* __restrict__ g,
                                              const float* __restrict__ be,
                                              const float* __restrict__ W,
                                              unsigned short* __restrict__ Wb,
                                              float* __restrict__ tw, float invN) {
  const int j = threadIdx.x;
  const int i0 = blockIdx.x * 16;
  const int nt = j >> 4;
  const int n = j & 15;
  float acc = 0.f;
#pragma unroll
  for (int ii = 0; ii < 16; ii++) {
    int i = i0 + ii;
    float m = stats[i] * invN;
    float var = stats[128 + i] * invN - m * m;
    float si = g[i] * rsqrtf(var + 1e-5f);
    float ti = be[i] - m * si;
    float w = W[i * 128 + j];
    acc += ti * w;
    int kt = i >> 5, quad = (i >> 3) & 3, jj = i & 7;
    Wb[((((kt * 8 + nt) * 4 + quad) * 16 + n) << 3) + jj] =
        (unsigned short)bf16_rn(si * w);
  }
  atomicAdd(&tw[j], acc);
}

// out[g] = pacc[g]/cnt(g) + bout; cnt via binary search on SORTED batch (R15:
// k_cntg fused here).
__global__ __launch_bounds__(256) void k_out(const float* __restrict__ pacc,
                                             const int* __restrict__ batch,
                                             const float* __restrict__ bout,
                                             float* __restrict__ out,
                                             int N, int G) {
  int g = blockIdx.x * 256 + threadIdx.x;
  if (g >= G) return;
  int lo = 0, hi = N;
  while (lo < hi) { int mid = (lo + hi) >> 1; if (batch[mid] < g) lo = mid + 1; else hi = mid; }
  int a = lo;
  hi = N;
  while (lo < hi) { int mid = (lo + hi) >> 1; if (batch[mid] < g + 1) lo = mid + 1; else hi = mid; }
  float cnt = (float)(lo - a);
  out[g] = pacc[g] / fmaxf(cnt, 1.0f) + bout[0];
}

extern "C" void kernel_launch(void* const* d_in, const int* in_sizes, int n_in,
                              void* d_out, int out_size, void* d_ws, size_t ws_size,
                              hipStream_t stream) {
  const float* x    = (const float*)d_in[0];
  const int*   ei   = (const int*)d_in[1];
  const int*   batch= (const int*)d_in[2];
  const float* W0   = (const float*)d_in[3];
  const float* b0   = (const float*)d_in[4];
  const float* W1   = (const float*)d_in[5];
  const float* b1   = (const float*)d_in[6];
  const float* W2   = (const float*)d_in[7];
  const float* b2   = (const float*)d_in[8];
  const float* W3   = (const float*)d_in[9];
  const float* b3   = (const float*)d_in[10];
  const float* g1   = (const float*)d_in[11];
  const float* be1  = (const float*)d_in[12];
  const float* g2   = (const float*)d_in[13];
  const float* be2  = (const float*)d_in[14];
  const float* g3   = (const float*)d_in[15];
  const float* be3  = (const float*)d_in[16];
  const float* Wout = (const float*)d_in[17];
  const float* bout = (const float*)d_in[18];
  float* out = (float*)d_out;

  const int N = in_sizes[0] / 9;
  const int E = in_sizes[1] / 2;
  const int G = out_size;

  char* w = (char*)d_ws;
  auto alloc = [&](size_t bytes) -> void* {
    void* p = (void*)w;
    w += (bytes + 255) & ~(size_t)255;
    return p;
  };
  // ---- zeroed region (ONE memset) ----
  char* zbase = w;
  int*   cnt    = (int*)alloc((size_t)N * 4);
  float* pacc   = (float*)alloc((size_t)G * 4);
  float* stats  = (float*)alloc(3 * 256 * 4);
  float* tw3    = (float*)alloc(3 * 128 * 4);
  unsigned* cmU3 = (unsigned*)alloc(3 * 128 * 4);  // per-layer col absmax (bits)
  size_t zsize = (size_t)(w - zbase);
  // ---- non-zeroed ----
  int*   offs   = (int*)alloc((size_t)N * 4);
  int*   incl   = (int*)alloc((size_t)N * 4);
  int*   bsums  = (int*)alloc(512 * 4);
  int*   bpref  = (int*)alloc(512 * 4);
  float* dinv   = (float*)alloc((size_t)N * 4);
  float2* dq    = (float2*)alloc((size_t)N * 8);
  int2*  meta   = (int2*)alloc((size_t)N * 8);
  int*   rank   = (int*)alloc((size_t)E * 4);
  int*   rows   = (int*)alloc((size_t)E * 4);
  unsigned short* Wb = (unsigned short*)alloc(128 * 128 * 2);  // bf16 B-frag layout
  unsigned* u   = (unsigned*)alloc((size_t)N * 16 * 2);        // bf16, 32B rows
  float* ax     = (float*)alloc((size_t)N * 12 * 4);
  unsigned* Lb  = (unsigned*)alloc((size_t)N * 128 * 2);       // bf16 rows, 256B
  unsigned* L8  = (unsigned*)alloc((size_t)N * 128);           // int8 rows, 128B
  unsigned short* Abuf = (unsigned short*)alloc((size_t)N * 128 * 2);  // bf16 acts
  const int sb  = (N + 15) / 16;    // spmm / spmm9 / gemm_in blocks
  float* part   = (float*)alloc((size_t)sb * 256 * 4);  // per-block BN partials

  hipMemsetAsync(zbase, 0, zsize, stream);

  const int eb  = (E + 255) / 256;
  const int nbN = (N + 255) / 256;  // also the scan block count (must be <= 512)
  const int mb  = (N + 63) / 64;    // mfma gemm blocks
  const int qb  = (N * 4 + 255) / 256;  // quant blocks
  const float invN = 1.0f / (float)N;
  float* twA = tw3;
  float* twB = tw3 + 128;
  float* twC = tw3 + 256;
  unsigned* cmA = cmU3;
  unsigned* cmB = cmU3 + 128;
  unsigned* cmC = cmU3 + 256;

  // --- graph preprocessing ---
  k_count<<<eb, 256, 0, stream>>>(ei, cnt, rank, E);
  k_scan1<<<nbN, 256, 0, stream>>>(cnt, incl, bsums, dinv, N);
  k_scan2<<<1, 512, 0, stream>>>(bsums, bpref, nbN);
  k_scan3_prep<<<nbN, 256, 0, stream>>>(incl, cnt, bpref, offs, meta, x, dinv, u, N);
  k_csr<<<eb, 256, 0, stream>>>(ei, offs, rank, rows, E);

  // --- layer 1: aggregate 9-dim input first (A x) @ W0; also emits dq ---
  k_spmm9<<<sb, 256, 0, stream>>>((const unsigned short*)u, meta, rows,
                                  dinv, ax, dq, N);
  k_gemm_in<<<sb, 256, 0, stream>>>(ax, W0, b0, Abuf, part, N);
  k_redstats<<<128, 256, 0, stream>>>(part, stats, sb);
  // --- layer 2 ---
  k_fold<<<8, 128, 0, stream>>>(stats, g1, be1, W1, Wb, twA, invN);
  k_gemm_mfma<<<mb, 256, 0, stream>>>(Abuf, (const uint4*)Wb, dinv,
                                      (unsigned short*)Lb, cmA, N);
  k_quant<<<qb, 256, 0, stream>>>((const unsigned short*)Lb, cmA, L8, N * 4);
  k_spmm<0><<<sb, 256, 0, stream>>>(Lb, L8, cmA, meta, rows, dq, twA, b1,
                                    Abuf, part, nullptr, nullptr, nullptr, N);
  k_redstats<<<128, 256, 0, stream>>>(part, stats + 256, sb);
  // --- layer 3 ---
  k_fold<<<8, 128, 0, stream>>>(stats + 256, g2, be2, W2, Wb, twB, invN);
  k_gemm_mfma<<<mb, 256, 0, stream>>>(Abuf, (const uint4*)Wb, dinv,
                                      (unsigned short*)Lb, cmB, N);
  k_quant<<<qb, 256, 0, stream>>>((const unsigned short*)Lb, cmB, L8, N * 4);
  k_spmm<0><<<sb, 256, 0, stream>>>(Lb, L8, cmB, meta, rows, dq, twB, b2,
                                    Abuf, part, nullptr, nullptr, nullptr, N);
  k_redstats<<<128, 256, 0, stream>>>(part, stats + 512, sb);
  // --- layer 4 (+ fused pool @ Wout) ---
  k_fold<<<8, 128, 0, stream>>>(stats + 512, g3, be3, W3, Wb, twC, invN);
  k_gemm_mfma<<<mb, 256, 0, stream>>>(Abuf, (const uint4*)Wb, dinv,
                                      (unsigned short*)Lb, cmC, N);
  k_quant<<<qb, 256, 0, stream>>>((const unsigned short*)Lb, cmC, L8, N * 4);
  k_spmm<1><<<sb, 256, 0, stream>>>(Lb, L8, cmC, meta, rows, dq, twC, b3,
                                    nullptr, nullptr, Wout, batch, pacc, N);
  k_out<<<(G + 255) / 256, 256, 0, stream>>>(pacc, batch, bout, out, N, G);
}